// Round 10
// baseline (1798.752 us; speedup 1.0000x reference)
//
#include <hip/hip_runtime.h>
#include <math.h>

#define D_MODEL 256
#define NHEAD   8
#define D_K     32
#define LSEQ    2048
#define BATCH   2
#define ROWS    (BATCH * LSEQ)   // 4096
#define D_FF    1024
#define UTOP    38
#define CAP     128

// ---------------------------------------------------------------------------
// Embedding + positional encoding
// ---------------------------------------------------------------------------
__global__ __launch_bounds__(256) void k_embed(const float* __restrict__ x,
                                               const float* __restrict__ w,
                                               const float* __restrict__ b,
                                               float* __restrict__ h) {
    int row = blockIdx.x;           // b*L + l
    int l   = row & (LSEQ - 1);
    int d   = threadIdx.x;
    __shared__ float xs[32];
    if (d < 32) xs[d] = x[row * 32 + d];
    __syncthreads();
    float acc = 0.f;
#pragma unroll
    for (int i = 0; i < 32; ++i) acc += xs[i] * w[i * D_MODEL + d];
    acc = (acc + b[d]) * 16.0f;     // sqrt(256)
    int m = d >> 1;
    float div = expf(-(float)(2 * m) * (9.210340371976184f / 256.0f)); // ln(1e4)/256
    float ang = (float)l * div;
    float pe = (d & 1) ? cosf(ang) : sinf(ang);
    h[row * D_MODEL + d] = acc + pe;
}

// ---------------------------------------------------------------------------
// Shared fp32 tiled GEMM body: C[64x64 tile] = A[M,K(lda)] @ W[K,N] (+ bias)
// MODE 0: plain   MODE 1: relu   MODE 2: scatter to q/k/v layout [B,H,L,32]
// ---------------------------------------------------------------------------
template <int MODE>
__device__ __forceinline__ void gemm_body(const float* __restrict__ A, int lda,
                                          const float* __restrict__ W, int N,
                                          const float* __restrict__ bias, bool doBias,
                                          float* __restrict__ C, int K,
                                          int m0, int n0) {
    __shared__ float As[16][68];
    __shared__ float Ws[16][68];
    const int t  = threadIdx.x;
    const int tx = t & 15, ty = t >> 4;
    float acc[4][4] = {};
    for (int k0 = 0; k0 < K; k0 += 16) {
        {
            int mr = t >> 2, kc = (t & 3) * 4;
            float4 av = *(const float4*)&A[(size_t)(m0 + mr) * lda + k0 + kc];
            As[kc + 0][mr] = av.x; As[kc + 1][mr] = av.y;
            As[kc + 2][mr] = av.z; As[kc + 3][mr] = av.w;
            int kr = t >> 4, nc = (t & 15) * 4;
            *(float4*)&Ws[kr][nc] = *(const float4*)&W[(size_t)(k0 + kr) * N + n0 + nc];
        }
        __syncthreads();
#pragma unroll
        for (int k = 0; k < 16; ++k) {
            float4 a4 = *(const float4*)&As[k][ty * 4];
            float4 w4 = *(const float4*)&Ws[k][tx * 4];
            float av[4] = {a4.x, a4.y, a4.z, a4.w};
            float wv[4] = {w4.x, w4.y, w4.z, w4.w};
#pragma unroll
            for (int i = 0; i < 4; ++i)
#pragma unroll
                for (int j = 0; j < 4; ++j) acc[i][j] += av[i] * wv[j];
        }
        __syncthreads();
    }
#pragma unroll
    for (int i = 0; i < 4; ++i) {
        int row = m0 + ty * 4 + i;
#pragma unroll
        for (int j = 0; j < 4; ++j) {
            int col = n0 + tx * 4 + j;
            float v = acc[i][j];
            if (doBias) v += bias[col];
            if (MODE == 1) v = fmaxf(v, 0.f);
            if (MODE == 2) {
                int bb = row >> 11, ll = row & (LSEQ - 1);
                int hh = col >> 5, dd = col & 31;
                C[(((size_t)(bb * NHEAD + hh) * LSEQ) + ll) * D_K + dd] = v;
            } else {
                C[(size_t)row * N + col] = v;
            }
        }
    }
}

// QKV fused: blockIdx.z selects {wq,wk,wv}; scatters to [B,H,L,32] at out+z*1M.
__global__ __launch_bounds__(256) void k_qkv(const float* __restrict__ A,
                                             const float* __restrict__ wq,
                                             const float* __restrict__ wk,
                                             const float* __restrict__ wv,
                                             const float* __restrict__ bq,
                                             const float* __restrict__ bk,
                                             const float* __restrict__ bv,
                                             float* __restrict__ out) {
    int z = blockIdx.z;
    const float* W = z == 0 ? wq : (z == 1 ? wk : wv);
    const float* B = z == 0 ? bq : (z == 1 ? bk : bv);
    gemm_body<2>(A, 256, W, 256, B, true, out + (size_t)z * (1 << 20), 256,
                 blockIdx.x * 64, blockIdx.y * 64);
}

// split-K GEMM: blockIdx.z = K-half; partial z to Cbase + z*1M; bias on z=0 only.
__global__ __launch_bounds__(256) void k_gemm_sk(const float* __restrict__ A, int lda,
                                                 const float* __restrict__ W,
                                                 const float* __restrict__ bias,
                                                 float* __restrict__ Cbase,
                                                 int N, int Ksub) {
    int z = blockIdx.z;
    gemm_body<0>(A + (size_t)z * Ksub, lda, W + (size_t)z * Ksub * N, N, bias, z == 0,
                 Cbase + (size_t)z * (1 << 20), Ksub, blockIdx.x * 64, blockIdx.y * 64);
}

// ff1: relu GEMM, N=1024
__global__ __launch_bounds__(256) void k_ff1(const float* __restrict__ A,
                                             const float* __restrict__ W,
                                             const float* __restrict__ bias,
                                             float* __restrict__ C) {
    gemm_body<1>(A, 256, W, 1024, bias, true, C, 256, blockIdx.x * 64, blockIdx.y * 64);
}

// ---------------------------------------------------------------------------
// Fused ProbSparse attention, v8 — pivot select, CAP 128, 5 blocks/CU.
// Identical algorithm to v7 (verified): two QK passes over LDS-staged K,
// pivot = 38th-largest of 64 lane-maxes (bitonic), push candidates >= pivot,
// exact 4-bit x 8-pass radix threshold over the list, softmax + PV gather.
// LDS ~29 KB: CAP 240->128 (E[cand]=56, sd 7.4; max over 65K rows ~91),
// ushort indices, 16-bin histogram.
// ---------------------------------------------------------------------------
__device__ __forceinline__ unsigned int sortkey(float f) {
    unsigned int u = __float_as_uint(f);
    return (u & 0x80000000u) ? ~u : (u | 0x80000000u);
}
__device__ __forceinline__ float key2f(unsigned int u) {
    unsigned int b = (u & 0x80000000u) ? (u ^ 0x80000000u) : ~u;
    return __uint_as_float(b);
}
__device__ __forceinline__ void gload_lds16(const float* src, float* ldsDst) {
    __builtin_amdgcn_global_load_lds(
        (const __attribute__((address_space(1))) unsigned int*)src,
        (__attribute__((address_space(3))) unsigned int*)ldsDst,
        16, 0, 0);
}

__global__ __launch_bounds__(256, 5) void k_attn(const float* __restrict__ Q,
                                                 const float* __restrict__ Kt,
                                                 const float* __restrict__ Vt,
                                                 float* __restrict__ ctxb) {
    __shared__ float          Kl[2][2048];      // 16 KB   K tile double-buffer
    __shared__ unsigned int   lvk[4][4][CAP];   // 8 KB    candidate keys
    __shared__ unsigned short lix[4][4][CAP];   // 4 KB    candidate indices
    __shared__ int            bins[4][16];      // 256 B   radix bins
    __shared__ int            lcnt[4][4];

    const int tid   = threadIdx.x;
    const int lane  = tid & 63;
    const int wid   = tid >> 6;
    // XCD-aware swizzle: grid 2048 = 8 XCDs x 256; same bh stays on one XCD.
    const int lbid  = (blockIdx.x & 7) * 256 + (blockIdx.x >> 3);
    const int bh    = lbid >> 7;                // 16 bh x 128 chunks
    const int chunk = lbid & 127;
    const int row0  = chunk * 16 + wid * 4;     // 4 rows per wave
    const int b     = bh >> 3, hh = bh & 7;
    const int h     = lane >> 5;                // d-half owned by this lane
    const int p     = lane & 31;

    const float* Kb = Kt + (size_t)bh * LSEQ * D_K;
    const float* Vb = Vt + (size_t)bh * LSEQ * D_K;
    const float* qp = Q + ((size_t)bh * LSEQ + row0) * D_K;

    const float scale = 0.17677669529663687f;   // 1/sqrt(32)
    float q[4][16];
#pragma unroll
    for (int r = 0; r < 4; ++r)
#pragma unroll
        for (int i = 0; i < 16; ++i)
            q[r][i] = qp[r * 32 + h * 16 + i] * scale;

    // ---- PASS 1: dots, track lane-max per row --------------------------
    unsigned int lmax[4];
#pragma unroll
    for (int r = 0; r < 4; ++r) lmax[r] = 0u;

#pragma unroll
    for (int i = 0; i < 2; ++i) {
        int r  = wid * 2 + i;
        int kk = r >> 2, cc = r & 3;
        gload_lds16(Kb + ((size_t)(2 * p + kk)) * 32 + h * 16 + cc * 4, &Kl[0][r * 256]);
    }
    asm volatile("s_waitcnt vmcnt(0)" ::: "memory");
    __syncthreads();

    for (int t = 0; t < 32; ++t) {
        const int buf = t & 1;
        if (t < 31) {
#pragma unroll
            for (int i = 0; i < 2; ++i) {
                int r  = wid * 2 + i;
                int kk = r >> 2, cc = r & 3;
                gload_lds16(Kb + ((size_t)((t + 1) * 64 + 2 * p + kk)) * 32 + h * 16 + cc * 4,
                            &Kl[buf ^ 1][r * 256]);
            }
        }
        float a[4], e[4];
#pragma unroll
        for (int r = 0; r < 4; ++r) { a[r] = 0.f; e[r] = 0.f; }
#pragma unroll
        for (int c = 0; c < 4; ++c) {
            float4 kva = *(const float4*)&Kl[buf][c * 256 + lane * 4];        // key 2p
            float4 kvb = *(const float4*)&Kl[buf][(4 + c) * 256 + lane * 4];  // key 2p+1
#pragma unroll
            for (int r = 0; r < 4; ++r) {
                a[r] += q[r][c*4+0]*kva.x + q[r][c*4+1]*kva.y + q[r][c*4+2]*kva.z + q[r][c*4+3]*kva.w;
                e[r] += q[r][c*4+0]*kvb.x + q[r][c*4+1]*kvb.y + q[r][c*4+2]*kvb.z + q[r][c*4+3]*kvb.w;
            }
        }
#pragma unroll
        for (int r = 0; r < 4; ++r) {
            float fa = a[r] + __shfl_xor(a[r], 32);
            float fe = e[r] + __shfl_xor(e[r], 32);
            unsigned int k = sortkey(h ? fe : fa);   // lane owns key 2p+h
            if (k > lmax[r]) lmax[r] = k;
        }
        asm volatile("s_waitcnt vmcnt(0)" ::: "memory");
        __syncthreads();
    }

    // ---- pivot per row: bitonic-sort 64 lane-maxes, broadcast via shfl --
    unsigned int Tpiv[4];
    float        rmaxf[4];
#pragma unroll
    for (int r = 0; r < 4; ++r) {
        unsigned int v = lmax[r];
#pragma unroll
        for (int k = 2; k <= 64; k <<= 1) {
#pragma unroll
            for (int j = k >> 1; j >= 1; j >>= 1) {
                unsigned int pv = (unsigned int)__shfl_xor((int)v, j);
                bool lower = ((lane & j) == 0);
                bool up    = ((lane & k) == 0);
                unsigned int mn = v < pv ? v : pv;
                unsigned int mx = v < pv ? pv : v;
                v = (lower == up) ? mn : mx;
            }
        }
        Tpiv[r]  = (unsigned int)__shfl((int)v, 26);  // 38th-largest lane-max
        rmaxf[r] = key2f((unsigned int)__shfl((int)v, 63));
    }
    if (lane < 4) lcnt[wid][lane] = 0;

    // ---- PASS 2: recompute dots, push candidates >= pivot --------------
#pragma unroll
    for (int i = 0; i < 2; ++i) {
        int r  = wid * 2 + i;
        int kk = r >> 2, cc = r & 3;
        gload_lds16(Kb + ((size_t)(2 * p + kk)) * 32 + h * 16 + cc * 4, &Kl[0][r * 256]);
    }
    asm volatile("s_waitcnt vmcnt(0)" ::: "memory");
    __syncthreads();

    for (int t = 0; t < 32; ++t) {
        const int buf = t & 1;
        if (t < 31) {
#pragma unroll
            for (int i = 0; i < 2; ++i) {
                int r  = wid * 2 + i;
                int kk = r >> 2, cc = r & 3;
                gload_lds16(Kb + ((size_t)((t + 1) * 64 + 2 * p + kk)) * 32 + h * 16 + cc * 4,
                            &Kl[buf ^ 1][r * 256]);
            }
        }
        float a[4], e[4];
#pragma unroll
        for (int r = 0; r < 4; ++r) { a[r] = 0.f; e[r] = 0.f; }
#pragma unroll
        for (int c = 0; c < 4; ++c) {
            float4 kva = *(const float4*)&Kl[buf][c * 256 + lane * 4];
            float4 kvb = *(const float4*)&Kl[buf][(4 + c) * 256 + lane * 4];
#pragma unroll
            for (int r = 0; r < 4; ++r) {
                a[r] += q[r][c*4+0]*kva.x + q[r][c*4+1]*kva.y + q[r][c*4+2]*kva.z + q[r][c*4+3]*kva.w;
                e[r] += q[r][c*4+0]*kvb.x + q[r][c*4+1]*kvb.y + q[r][c*4+2]*kvb.z + q[r][c*4+3]*kvb.w;
            }
        }
        const int kidx = t * 64 + 2 * p + h;
#pragma unroll
        for (int r = 0; r < 4; ++r) {
            float fa = a[r] + __shfl_xor(a[r], 32);
            float fe = e[r] + __shfl_xor(e[r], 32);
            unsigned int k = sortkey(h ? fe : fa);
            if (k >= Tpiv[r]) {
                int slot = atomicAdd(&lcnt[wid][r], 1);
                if (slot < CAP) {
                    lvk[wid][r][slot] = k;
                    lix[wid][r][slot] = (unsigned short)kidx;
                }
            }
        }
        asm volatile("s_waitcnt vmcnt(0)" ::: "memory");
        __syncthreads();
    }

    // ---- per-row: exact 4-bit radix select, softmax, PV ----------------
    for (int r = 0; r < 4; ++r) {
        int cnt = lcnt[wid][r]; if (cnt > CAP) cnt = CAP;

        unsigned int prefix = 0;
        int need = UTOP;
#pragma unroll
        for (int pass = 0; pass < 8; ++pass) {
            const int sh = 28 - pass * 4;
            if (lane < 16) bins[wid][lane] = 0;
            for (int i = lane; i < cnt; i += 64) {
                unsigned int key = lvk[wid][r][i];
                bool msk = (pass == 0) || ((key >> (sh + 4)) == (prefix >> (sh + 4)));
                if (msk) atomicAdd(&bins[wid][(key >> sh) & 15], 1);
            }
            int c = (lane < 16) ? bins[wid][lane] : 0;
            int suf = c;
#pragma unroll
            for (int off = 1; off < 16; off <<= 1) {
                int o = __shfl_down(suf, off);
                suf += (lane + off < 16) ? o : 0;
            }
            int above = suf - c;    // count in strictly-higher bins
            bool found = (lane < 16) && (above < need) && (above + c >= need);
            unsigned int cp = prefix | ((unsigned int)lane << sh);
            int cn = need - above;
            unsigned long long bal = __ballot(found);
            int wl = (int)(__ffsll(bal) - 1);
            prefix = (unsigned int)__shfl((int)cp, wl);
            need   = __shfl(cn, wl);
        }
        const unsigned int thrkey = prefix;   // exact 38th-largest key

        float psum = 0.f;
        for (int i = lane; i < cnt; i += 64) {
            unsigned int key = lvk[wid][r][i];
            if (key >= thrkey) psum += expf(key2f(key) - rmaxf[r]);
        }
#pragma unroll
        for (int off = 32; off >= 1; off >>= 1) psum += __shfl_xor(psum, off);
        float inv = 1.0f / psum;

        float acc = 0.f;
        for (int i = h; i < cnt; i += 2) {
            unsigned int key = lvk[wid][r][i];
            float w = (key >= thrkey) ? expf(key2f(key) - rmaxf[r]) : 0.f;
            acc += w * Vb[(size_t)lix[wid][r][i] * D_K + p];
        }
        acc += __shfl_xor(acc, 32);
        if (lane < 32)
            ctxb[((size_t)(b * LSEQ) + row0 + r) * D_MODEL + hh * D_K + p] = acc * inv;
    }
}

// ---------------------------------------------------------------------------
// Residual add (two partials) + LayerNorm over 256, in place into h.
// ---------------------------------------------------------------------------
__global__ __launch_bounds__(64) void k_addln2(float* __restrict__ h,
                                               const float* __restrict__ a1,
                                               const float* __restrict__ a2,
                                               const float* __restrict__ g,
                                               const float* __restrict__ bb) {
    int row = blockIdx.x, lane = threadIdx.x;
    float4 hv = *(const float4*)&h[(size_t)row * D_MODEL + lane * 4];
    float4 v1 = *(const float4*)&a1[(size_t)row * D_MODEL + lane * 4];
    float4 v2 = *(const float4*)&a2[(size_t)row * D_MODEL + lane * 4];
    float x0 = hv.x + v1.x + v2.x, x1 = hv.y + v1.y + v2.y;
    float x2 = hv.z + v1.z + v2.z, x3 = hv.w + v1.w + v2.w;
    float s = x0 + x1 + x2 + x3;
#pragma unroll
    for (int off = 32; off >= 1; off >>= 1) s += __shfl_xor(s, off);
    float mean = s * (1.0f / 256.0f);
    float d0 = x0 - mean, d1 = x1 - mean, d2 = x2 - mean, d3 = x3 - mean;
    float vs = d0 * d0 + d1 * d1 + d2 * d2 + d3 * d3;
#pragma unroll
    for (int off = 32; off >= 1; off >>= 1) vs += __shfl_xor(vs, off);
    float inv = rsqrtf(vs * (1.0f / 256.0f) + 1e-5f);
    float4 gv = *(const float4*)&g[lane * 4];
    float4 bv = *(const float4*)&bb[lane * 4];
    float4 o;
    o.x = d0 * inv * gv.x + bv.x;
    o.y = d1 * inv * gv.y + bv.y;
    o.z = d2 * inv * gv.z + bv.z;
    o.w = d3 * inv * gv.w + bv.w;
    *(float4*)&h[(size_t)row * D_MODEL + lane * 4] = o;
}

// ---------------------------------------------------------------------------
// Decoder head
// ---------------------------------------------------------------------------
__global__ __launch_bounds__(64) void k_dec(const float* __restrict__ h,
                                            const float* __restrict__ w,
                                            const float* __restrict__ b,
                                            float* __restrict__ out) {
    int row = blockIdx.x, lane = threadIdx.x;
    int c = lane & 7, part = lane >> 3;   // 8 parts x 32 dims
    float acc = 0.f;
    int d0 = part * 32;
#pragma unroll
    for (int dd = 0; dd < 32; ++dd) acc += h[(size_t)row * D_MODEL + d0 + dd] * w[(d0 + dd) * 8 + c];
    acc += __shfl_xor(acc, 8);
    acc += __shfl_xor(acc, 16);
    acc += __shfl_xor(acc, 32);
    if (lane < 8) out[(size_t)row * 8 + c] = acc + b[c];
}

// ---------------------------------------------------------------------------
extern "C" void kernel_launch(void* const* d_in, const int* in_sizes, int n_in,
                              void* d_out, int out_size, void* d_ws, size_t ws_size,
                              hipStream_t stream) {
    const float* x     = (const float*)d_in[0];
    const float* emb_w = (const float*)d_in[1];
    const float* emb_b = (const float*)d_in[2];
    const float* wq    = (const float*)d_in[3];
    const float* bq    = (const float*)d_in[4];
    const float* wk    = (const float*)d_in[5];
    const float* bk    = (const float*)d_in[6];
    const float* wv    = (const float*)d_in[7];
    const float* bv    = (const float*)d_in[8];
    const float* wo    = (const float*)d_in[9];
    const float* bo    = (const float*)d_in[10];
    const float* ln1_g = (const float*)d_in[11];
    const float* ln1_b = (const float*)d_in[12];
    const float* ln2_g = (const float*)d_in[13];
    const float* ln2_b = (const float*)d_in[14];
    const float* ff1_w = (const float*)d_in[15];
    const float* ff1_b = (const float*)d_in[16];
    const float* ff2_w = (const float*)d_in[17];
    const float* ff2_b = (const float*)d_in[18];
    const float* dec_w = (const float*)d_in[19];
    const float* dec_b = (const float*)d_in[20];

    float* ws   = (float*)d_ws;
    float* h    = ws;                      // 4096*256   = 1M floats
    float* qb   = h    + (1 << 20);        // qb/kb/vb: [B,H,L,32] each 1M
    float* kb   = qb   + (1 << 20);
    float* vb   = kb   + (1 << 20);
    float* ctxb = vb   + (1 << 20);
    float* ffb  = ctxb + (1 << 20);        // 4096*1024 = 4M

    k_embed<<<ROWS, 256, 0, stream>>>(x, emb_w, emb_b, h);

    for (int l = 0; l < 2; ++l) {
        const float* wql = wq + (size_t)l * 65536;  const float* bql = bq + l * 256;
        const float* wkl = wk + (size_t)l * 65536;  const float* bkl = bk + l * 256;
        const float* wvl = wv + (size_t)l * 65536;  const float* bvl = bv + l * 256;
        const float* wol = wo + (size_t)l * 65536;  const float* bol = bo + l * 256;

        dim3 gq(64, 4, 3);
        k_qkv<<<gq, 256, 0, stream>>>(h, wql, wkl, wvl, bql, bkl, bvl, qb);

        k_attn<<<NHEAD * BATCH * 128, 256, 0, stream>>>(qb, kb, vb, ctxb);

        // wo: split-K (128 x 2) -> partials in qb, kb (free after attn)
        dim3 gsk(64, 4, 2);
        k_gemm_sk<<<gsk, 256, 0, stream>>>(ctxb, 256, wol, bol, qb, 256, 128);
        k_addln2<<<ROWS, 64, 0, stream>>>(h, qb, kb, ln1_g + l * 256, ln1_b + l * 256);

        dim3 gf1(64, 16);
        k_ff1<<<gf1, 256, 0, stream>>>(h, ff1_w + (size_t)l * 262144, ff1_b + l * 1024, ffb);

        // ff2: split-K (512 x 2) -> partials in qb, kb
        k_gemm_sk<<<gsk, 256, 0, stream>>>(ffb, 1024, ff2_w + (size_t)l * 262144,
                                           ff2_b + l * 256, qb, 256, 512);
        k_addln2<<<ROWS, 64, 0, stream>>>(h, qb, kb, ln2_g + l * 256, ln2_b + l * 256);
    }

    k_dec<<<ROWS, 64, 0, stream>>>(h, dec_w, dec_b, (float*)d_out);
}

// Round 11
// 976.361 us; speedup vs baseline: 1.8423x; 1.8423x over previous
//
#include <hip/hip_runtime.h>
#include <math.h>

#define D_MODEL 256
#define NHEAD   8
#define D_K     32
#define LSEQ    2048
#define BATCH   2
#define ROWS    (BATCH * LSEQ)   // 4096
#define D_FF    1024
#define UTOP    38
#define CAP     128

// ---------------------------------------------------------------------------
// Embedding + positional encoding
// ---------------------------------------------------------------------------
__global__ __launch_bounds__(256) void k_embed(const float* __restrict__ x,
                                               const float* __restrict__ w,
                                               const float* __restrict__ b,
                                               float* __restrict__ h) {
    int row = blockIdx.x;           // b*L + l
    int l   = row & (LSEQ - 1);
    int d   = threadIdx.x;
    __shared__ float xs[32];
    if (d < 32) xs[d] = x[row * 32 + d];
    __syncthreads();
    float acc = 0.f;
#pragma unroll
    for (int i = 0; i < 32; ++i) acc += xs[i] * w[i * D_MODEL + d];
    acc = (acc + b[d]) * 16.0f;     // sqrt(256)
    int m = d >> 1;
    float div = expf(-(float)(2 * m) * (9.210340371976184f / 256.0f)); // ln(1e4)/256
    float ang = (float)l * div;
    float pe = (d & 1) ? cosf(ang) : sinf(ang);
    h[row * D_MODEL + d] = acc + pe;
}

// ---------------------------------------------------------------------------
// Shared fp32 tiled GEMM body: C[64x64 tile] = A[M,K(lda)] @ W[K,N] (+ bias)
// MODE 0: plain   MODE 1: relu   MODE 2: scatter to q/k/v layout [B,H,L,32]
// ---------------------------------------------------------------------------
template <int MODE>
__device__ __forceinline__ void gemm_body(const float* __restrict__ A, int lda,
                                          const float* __restrict__ W, int N,
                                          const float* __restrict__ bias, bool doBias,
                                          float* __restrict__ C, int K,
                                          int m0, int n0) {
    __shared__ float As[16][68];
    __shared__ float Ws[16][68];
    const int t  = threadIdx.x;
    const int tx = t & 15, ty = t >> 4;
    float acc[4][4] = {};
    for (int k0 = 0; k0 < K; k0 += 16) {
        {
            int mr = t >> 2, kc = (t & 3) * 4;
            float4 av = *(const float4*)&A[(size_t)(m0 + mr) * lda + k0 + kc];
            As[kc + 0][mr] = av.x; As[kc + 1][mr] = av.y;
            As[kc + 2][mr] = av.z; As[kc + 3][mr] = av.w;
            int kr = t >> 4, nc = (t & 15) * 4;
            *(float4*)&Ws[kr][nc] = *(const float4*)&W[(size_t)(k0 + kr) * N + n0 + nc];
        }
        __syncthreads();
#pragma unroll
        for (int k = 0; k < 16; ++k) {
            float4 a4 = *(const float4*)&As[k][ty * 4];
            float4 w4 = *(const float4*)&Ws[k][tx * 4];
            float av[4] = {a4.x, a4.y, a4.z, a4.w};
            float wv[4] = {w4.x, w4.y, w4.z, w4.w};
#pragma unroll
            for (int i = 0; i < 4; ++i)
#pragma unroll
                for (int j = 0; j < 4; ++j) acc[i][j] += av[i] * wv[j];
        }
        __syncthreads();
    }
#pragma unroll
    for (int i = 0; i < 4; ++i) {
        int row = m0 + ty * 4 + i;
#pragma unroll
        for (int j = 0; j < 4; ++j) {
            int col = n0 + tx * 4 + j;
            float v = acc[i][j];
            if (doBias) v += bias[col];
            if (MODE == 1) v = fmaxf(v, 0.f);
            if (MODE == 2) {
                int bb = row >> 11, ll = row & (LSEQ - 1);
                int hh = col >> 5, dd = col & 31;
                C[(((size_t)(bb * NHEAD + hh) * LSEQ) + ll) * D_K + dd] = v;
            } else {
                C[(size_t)row * N + col] = v;
            }
        }
    }
}

// QKV fused: blockIdx.z selects {wq,wk,wv}; scatters to [B,H,L,32] at out+z*1M.
__global__ __launch_bounds__(256) void k_qkv(const float* __restrict__ A,
                                             const float* __restrict__ wq,
                                             const float* __restrict__ wk,
                                             const float* __restrict__ wv,
                                             const float* __restrict__ bq,
                                             const float* __restrict__ bk,
                                             const float* __restrict__ bv,
                                             float* __restrict__ out) {
    int z = blockIdx.z;
    const float* W = z == 0 ? wq : (z == 1 ? wk : wv);
    const float* B = z == 0 ? bq : (z == 1 ? bk : bv);
    gemm_body<2>(A, 256, W, 256, B, true, out + (size_t)z * (1 << 20), 256,
                 blockIdx.x * 64, blockIdx.y * 64);
}

// split-K GEMM: blockIdx.z = K-half; partial z to Cbase + z*1M; bias on z=0 only.
__global__ __launch_bounds__(256) void k_gemm_sk(const float* __restrict__ A, int lda,
                                                 const float* __restrict__ W,
                                                 const float* __restrict__ bias,
                                                 float* __restrict__ Cbase,
                                                 int N, int Ksub) {
    int z = blockIdx.z;
    gemm_body<0>(A + (size_t)z * Ksub, lda, W + (size_t)z * Ksub * N, N, bias, z == 0,
                 Cbase + (size_t)z * (1 << 20), Ksub, blockIdx.x * 64, blockIdx.y * 64);
}

// ff1: relu GEMM, N=1024
__global__ __launch_bounds__(256) void k_ff1(const float* __restrict__ A,
                                             const float* __restrict__ W,
                                             const float* __restrict__ bias,
                                             float* __restrict__ C) {
    gemm_body<1>(A, 256, W, 1024, bias, true, C, 256, blockIdx.x * 64, blockIdx.y * 64);
}

// ---------------------------------------------------------------------------
// Fused ProbSparse attention — pivot select, CAP 128.
// __launch_bounds__(256,4): VGPR budget 128 >= ~110 live -> NO SPILL (the
// (256,5) variant capped at ~96 VGPR and spilled; R10 post-mortem).
// LDS ~29 KB allows 5 blocks/CU; VGPR binds at 4 blocks/CU = 50% occupancy.
// ---------------------------------------------------------------------------
__device__ __forceinline__ unsigned int sortkey(float f) {
    unsigned int u = __float_as_uint(f);
    return (u & 0x80000000u) ? ~u : (u | 0x80000000u);
}
__device__ __forceinline__ float key2f(unsigned int u) {
    unsigned int b = (u & 0x80000000u) ? (u ^ 0x80000000u) : ~u;
    return __uint_as_float(b);
}
__device__ __forceinline__ void gload_lds16(const float* src, float* ldsDst) {
    __builtin_amdgcn_global_load_lds(
        (const __attribute__((address_space(1))) unsigned int*)src,
        (__attribute__((address_space(3))) unsigned int*)ldsDst,
        16, 0, 0);
}

__global__ __launch_bounds__(256, 4) void k_attn(const float* __restrict__ Q,
                                                 const float* __restrict__ Kt,
                                                 const float* __restrict__ Vt,
                                                 float* __restrict__ ctxb) {
    __shared__ float          Kl[2][2048];      // 16 KB   K tile double-buffer
    __shared__ unsigned int   lvk[4][4][CAP];   // 8 KB    candidate keys
    __shared__ unsigned short lix[4][4][CAP];   // 4 KB    candidate indices
    __shared__ int            bins[4][16];      // 256 B   radix bins
    __shared__ int            lcnt[4][4];

    const int tid   = threadIdx.x;
    const int lane  = tid & 63;
    const int wid   = tid >> 6;
    // XCD-aware swizzle: grid 2048 = 8 XCDs x 256; same bh stays on one XCD.
    const int lbid  = (blockIdx.x & 7) * 256 + (blockIdx.x >> 3);
    const int bh    = lbid >> 7;                // 16 bh x 128 chunks
    const int chunk = lbid & 127;
    const int row0  = chunk * 16 + wid * 4;     // 4 rows per wave
    const int b     = bh >> 3, hh = bh & 7;
    const int h     = lane >> 5;                // d-half owned by this lane
    const int p     = lane & 31;

    const float* Kb = Kt + (size_t)bh * LSEQ * D_K;
    const float* Vb = Vt + (size_t)bh * LSEQ * D_K;
    const float* qp = Q + ((size_t)bh * LSEQ + row0) * D_K;

    const float scale = 0.17677669529663687f;   // 1/sqrt(32)
    float q[4][16];
#pragma unroll
    for (int r = 0; r < 4; ++r)
#pragma unroll
        for (int i = 0; i < 16; ++i)
            q[r][i] = qp[r * 32 + h * 16 + i] * scale;

    // ---- PASS 1: dots, track lane-max per row --------------------------
    unsigned int lmax[4];
#pragma unroll
    for (int r = 0; r < 4; ++r) lmax[r] = 0u;

#pragma unroll
    for (int i = 0; i < 2; ++i) {
        int r  = wid * 2 + i;
        int kk = r >> 2, cc = r & 3;
        gload_lds16(Kb + ((size_t)(2 * p + kk)) * 32 + h * 16 + cc * 4, &Kl[0][r * 256]);
    }
    asm volatile("s_waitcnt vmcnt(0)" ::: "memory");
    __syncthreads();

    for (int t = 0; t < 32; ++t) {
        const int buf = t & 1;
        if (t < 31) {
#pragma unroll
            for (int i = 0; i < 2; ++i) {
                int r  = wid * 2 + i;
                int kk = r >> 2, cc = r & 3;
                gload_lds16(Kb + ((size_t)((t + 1) * 64 + 2 * p + kk)) * 32 + h * 16 + cc * 4,
                            &Kl[buf ^ 1][r * 256]);
            }
        }
        float a[4], e[4];
#pragma unroll
        for (int r = 0; r < 4; ++r) { a[r] = 0.f; e[r] = 0.f; }
#pragma unroll
        for (int c = 0; c < 4; ++c) {
            float4 kva = *(const float4*)&Kl[buf][c * 256 + lane * 4];        // key 2p
            float4 kvb = *(const float4*)&Kl[buf][(4 + c) * 256 + lane * 4];  // key 2p+1
#pragma unroll
            for (int r = 0; r < 4; ++r) {
                a[r] += q[r][c*4+0]*kva.x + q[r][c*4+1]*kva.y + q[r][c*4+2]*kva.z + q[r][c*4+3]*kva.w;
                e[r] += q[r][c*4+0]*kvb.x + q[r][c*4+1]*kvb.y + q[r][c*4+2]*kvb.z + q[r][c*4+3]*kvb.w;
            }
        }
#pragma unroll
        for (int r = 0; r < 4; ++r) {
            float fa = a[r] + __shfl_xor(a[r], 32);
            float fe = e[r] + __shfl_xor(e[r], 32);
            unsigned int k = sortkey(h ? fe : fa);   // lane owns key 2p+h
            if (k > lmax[r]) lmax[r] = k;
        }
        asm volatile("s_waitcnt vmcnt(0)" ::: "memory");
        __syncthreads();
    }

    // ---- pivot per row: bitonic-sort 64 lane-maxes, broadcast via shfl --
    unsigned int Tpiv[4];
    float        rmaxf[4];
#pragma unroll
    for (int r = 0; r < 4; ++r) {
        unsigned int v = lmax[r];
#pragma unroll
        for (int k = 2; k <= 64; k <<= 1) {
#pragma unroll
            for (int j = k >> 1; j >= 1; j >>= 1) {
                unsigned int pv = (unsigned int)__shfl_xor((int)v, j);
                bool lower = ((lane & j) == 0);
                bool up    = ((lane & k) == 0);
                unsigned int mn = v < pv ? v : pv;
                unsigned int mx = v < pv ? pv : v;
                v = (lower == up) ? mn : mx;
            }
        }
        Tpiv[r]  = (unsigned int)__shfl((int)v, 26);  // 38th-largest lane-max
        rmaxf[r] = key2f((unsigned int)__shfl((int)v, 63));
    }
    if (lane < 4) lcnt[wid][lane] = 0;

    // ---- PASS 2: recompute dots, push candidates >= pivot --------------
#pragma unroll
    for (int i = 0; i < 2; ++i) {
        int r  = wid * 2 + i;
        int kk = r >> 2, cc = r & 3;
        gload_lds16(Kb + ((size_t)(2 * p + kk)) * 32 + h * 16 + cc * 4, &Kl[0][r * 256]);
    }
    asm volatile("s_waitcnt vmcnt(0)" ::: "memory");
    __syncthreads();

    for (int t = 0; t < 32; ++t) {
        const int buf = t & 1;
        if (t < 31) {
#pragma unroll
            for (int i = 0; i < 2; ++i) {
                int r  = wid * 2 + i;
                int kk = r >> 2, cc = r & 3;
                gload_lds16(Kb + ((size_t)((t + 1) * 64 + 2 * p + kk)) * 32 + h * 16 + cc * 4,
                            &Kl[buf ^ 1][r * 256]);
            }
        }
        float a[4], e[4];
#pragma unroll
        for (int r = 0; r < 4; ++r) { a[r] = 0.f; e[r] = 0.f; }
#pragma unroll
        for (int c = 0; c < 4; ++c) {
            float4 kva = *(const float4*)&Kl[buf][c * 256 + lane * 4];
            float4 kvb = *(const float4*)&Kl[buf][(4 + c) * 256 + lane * 4];
#pragma unroll
            for (int r = 0; r < 4; ++r) {
                a[r] += q[r][c*4+0]*kva.x + q[r][c*4+1]*kva.y + q[r][c*4+2]*kva.z + q[r][c*4+3]*kva.w;
                e[r] += q[r][c*4+0]*kvb.x + q[r][c*4+1]*kvb.y + q[r][c*4+2]*kvb.z + q[r][c*4+3]*kvb.w;
            }
        }
        const int kidx = t * 64 + 2 * p + h;
#pragma unroll
        for (int r = 0; r < 4; ++r) {
            float fa = a[r] + __shfl_xor(a[r], 32);
            float fe = e[r] + __shfl_xor(e[r], 32);
            unsigned int k = sortkey(h ? fe : fa);
            if (k >= Tpiv[r]) {
                int slot = atomicAdd(&lcnt[wid][r], 1);
                if (slot < CAP) {
                    lvk[wid][r][slot] = k;
                    lix[wid][r][slot] = (unsigned short)kidx;
                }
            }
        }
        asm volatile("s_waitcnt vmcnt(0)" ::: "memory");
        __syncthreads();
    }

    // ---- per-row: exact 4-bit radix select, softmax, PV ----------------
    for (int r = 0; r < 4; ++r) {
        int cnt = lcnt[wid][r]; if (cnt > CAP) cnt = CAP;

        unsigned int prefix = 0;
        int need = UTOP;
#pragma unroll
        for (int pass = 0; pass < 8; ++pass) {
            const int sh = 28 - pass * 4;
            if (lane < 16) bins[wid][lane] = 0;
            for (int i = lane; i < cnt; i += 64) {
                unsigned int key = lvk[wid][r][i];
                bool msk = (pass == 0) || ((key >> (sh + 4)) == (prefix >> (sh + 4)));
                if (msk) atomicAdd(&bins[wid][(key >> sh) & 15], 1);
            }
            int c = (lane < 16) ? bins[wid][lane] : 0;
            int suf = c;
#pragma unroll
            for (int off = 1; off < 16; off <<= 1) {
                int o = __shfl_down(suf, off);
                suf += (lane + off < 16) ? o : 0;
            }
            int above = suf - c;    // count in strictly-higher bins
            bool found = (lane < 16) && (above < need) && (above + c >= need);
            unsigned int cp = prefix | ((unsigned int)lane << sh);
            int cn = need - above;
            unsigned long long bal = __ballot(found);
            int wl = (int)(__ffsll(bal) - 1);
            prefix = (unsigned int)__shfl((int)cp, wl);
            need   = __shfl(cn, wl);
        }
        const unsigned int thrkey = prefix;   // exact 38th-largest key

        float psum = 0.f;
        for (int i = lane; i < cnt; i += 64) {
            unsigned int key = lvk[wid][r][i];
            if (key >= thrkey) psum += expf(key2f(key) - rmaxf[r]);
        }
#pragma unroll
        for (int off = 32; off >= 1; off >>= 1) psum += __shfl_xor(psum, off);
        float inv = 1.0f / psum;

        float acc = 0.f;
        for (int i = h; i < cnt; i += 2) {
            unsigned int key = lvk[wid][r][i];
            float w = (key >= thrkey) ? expf(key2f(key) - rmaxf[r]) : 0.f;
            acc += w * Vb[(size_t)lix[wid][r][i] * D_K + p];
        }
        acc += __shfl_xor(acc, 32);
        if (lane < 32)
            ctxb[((size_t)(b * LSEQ) + row0 + r) * D_MODEL + hh * D_K + p] = acc * inv;
    }
}

// ---------------------------------------------------------------------------
// Residual add (two partials) + LayerNorm over 256, in place into h.
// ---------------------------------------------------------------------------
__global__ __launch_bounds__(64) void k_addln2(float* __restrict__ h,
                                               const float* __restrict__ a1,
                                               const float* __restrict__ a2,
                                               const float* __restrict__ g,
                                               const float* __restrict__ bb) {
    int row = blockIdx.x, lane = threadIdx.x;
    float4 hv = *(const float4*)&h[(size_t)row * D_MODEL + lane * 4];
    float4 v1 = *(const float4*)&a1[(size_t)row * D_MODEL + lane * 4];
    float4 v2 = *(const float4*)&a2[(size_t)row * D_MODEL + lane * 4];
    float x0 = hv.x + v1.x + v2.x, x1 = hv.y + v1.y + v2.y;
    float x2 = hv.z + v1.z + v2.z, x3 = hv.w + v1.w + v2.w;
    float s = x0 + x1 + x2 + x3;
#pragma unroll
    for (int off = 32; off >= 1; off >>= 1) s += __shfl_xor(s, off);
    float mean = s * (1.0f / 256.0f);
    float d0 = x0 - mean, d1 = x1 - mean, d2 = x2 - mean, d3 = x3 - mean;
    float vs = d0 * d0 + d1 * d1 + d2 * d2 + d3 * d3;
#pragma unroll
    for (int off = 32; off >= 1; off >>= 1) vs += __shfl_xor(vs, off);
    float inv = rsqrtf(vs * (1.0f / 256.0f) + 1e-5f);
    float4 gv = *(const float4*)&g[lane * 4];
    float4 bv = *(const float4*)&bb[lane * 4];
    float4 o;
    o.x = d0 * inv * gv.x + bv.x;
    o.y = d1 * inv * gv.y + bv.y;
    o.z = d2 * inv * gv.z + bv.z;
    o.w = d3 * inv * gv.w + bv.w;
    *(float4*)&h[(size_t)row * D_MODEL + lane * 4] = o;
}

// ---------------------------------------------------------------------------
// Decoder head
// ---------------------------------------------------------------------------
__global__ __launch_bounds__(64) void k_dec(const float* __restrict__ h,
                                            const float* __restrict__ w,
                                            const float* __restrict__ b,
                                            float* __restrict__ out) {
    int row = blockIdx.x, lane = threadIdx.x;
    int c = lane & 7, part = lane >> 3;   // 8 parts x 32 dims
    float acc = 0.f;
    int d0 = part * 32;
#pragma unroll
    for (int dd = 0; dd < 32; ++dd) acc += h[(size_t)row * D_MODEL + d0 + dd] * w[(d0 + dd) * 8 + c];
    acc += __shfl_xor(acc, 8);
    acc += __shfl_xor(acc, 16);
    acc += __shfl_xor(acc, 32);
    if (lane < 8) out[(size_t)row * 8 + c] = acc + b[c];
}

// ---------------------------------------------------------------------------
extern "C" void kernel_launch(void* const* d_in, const int* in_sizes, int n_in,
                              void* d_out, int out_size, void* d_ws, size_t ws_size,
                              hipStream_t stream) {
    const float* x     = (const float*)d_in[0];
    const float* emb_w = (const float*)d_in[1];
    const float* emb_b = (const float*)d_in[2];
    const float* wq    = (const float*)d_in[3];
    const float* bq    = (const float*)d_in[4];
    const float* wk    = (const float*)d_in[5];
    const float* bk    = (const float*)d_in[6];
    const float* wv    = (const float*)d_in[7];
    const float* bv    = (const float*)d_in[8];
    const float* wo    = (const float*)d_in[9];
    const float* bo    = (const float*)d_in[10];
    const float* ln1_g = (const float*)d_in[11];
    const float* ln1_b = (const float*)d_in[12];
    const float* ln2_g = (const float*)d_in[13];
    const float* ln2_b = (const float*)d_in[14];
    const float* ff1_w = (const float*)d_in[15];
    const float* ff1_b = (const float*)d_in[16];
    const float* ff2_w = (const float*)d_in[17];
    const float* ff2_b = (const float*)d_in[18];
    const float* dec_w = (const float*)d_in[19];
    const float* dec_b = (const float*)d_in[20];

    float* ws   = (float*)d_ws;
    float* h    = ws;                      // 4096*256   = 1M floats
    float* qb   = h    + (1 << 20);        // qb/kb/vb: [B,H,L,32] each 1M
    float* kb   = qb   + (1 << 20);
    float* vb   = kb   + (1 << 20);
    float* ctxb = vb   + (1 << 20);
    float* ffb  = ctxb + (1 << 20);        // 4096*1024 = 4M

    k_embed<<<ROWS, 256, 0, stream>>>(x, emb_w, emb_b, h);

    for (int l = 0; l < 2; ++l) {
        const float* wql = wq + (size_t)l * 65536;  const float* bql = bq + l * 256;
        const float* wkl = wk + (size_t)l * 65536;  const float* bkl = bk + l * 256;
        const float* wvl = wv + (size_t)l * 65536;  const float* bvl = bv + l * 256;
        const float* wol = wo + (size_t)l * 65536;  const float* bol = bo + l * 256;

        dim3 gq(64, 4, 3);
        k_qkv<<<gq, 256, 0, stream>>>(h, wql, wkl, wvl, bql, bkl, bvl, qb);

        k_attn<<<NHEAD * BATCH * 128, 256, 0, stream>>>(qb, kb, vb, ctxb);

        // wo: split-K (128 x 2) -> partials in qb, kb (free after attn)
        dim3 gsk(64, 4, 2);
        k_gemm_sk<<<gsk, 256, 0, stream>>>(ctxb, 256, wol, bol, qb, 256, 128);
        k_addln2<<<ROWS, 64, 0, stream>>>(h, qb, kb, ln1_g + l * 256, ln1_b + l * 256);

        dim3 gf1(64, 16);
        k_ff1<<<gf1, 256, 0, stream>>>(h, ff1_w + (size_t)l * 262144, ff1_b + l * 1024, ffb);

        // ff2: split-K (512 x 2) -> partials in qb, kb
        k_gemm_sk<<<gsk, 256, 0, stream>>>(ffb, 1024, ff2_w + (size_t)l * 262144,
                                           ff2_b + l * 256, qb, 256, 512);
        k_addln2<<<ROWS, 64, 0, stream>>>(h, qb, kb, ln2_g + l * 256, ln2_b + l * 256);
    }

    k_dec<<<ROWS, 64, 0, stream>>>(h, dec_w, dec_b, (float*)d_out);
}

// Round 12
// 956.466 us; speedup vs baseline: 1.8806x; 1.0208x over previous
//
#include <hip/hip_runtime.h>
#include <math.h>

#define D_MODEL 256
#define NHEAD   8
#define D_K     32
#define LSEQ    2048
#define BATCH   2
#define ROWS    (BATCH * LSEQ)   // 4096
#define D_FF    1024
#define UTOP    38
#define CAP     128

// ---------------------------------------------------------------------------
// Embedding + positional encoding
// ---------------------------------------------------------------------------
__global__ __launch_bounds__(256) void k_embed(const float* __restrict__ x,
                                               const float* __restrict__ w,
                                               const float* __restrict__ b,
                                               float* __restrict__ h) {
    int row = blockIdx.x;           // b*L + l
    int l   = row & (LSEQ - 1);
    int d   = threadIdx.x;
    __shared__ float xs[32];
    if (d < 32) xs[d] = x[row * 32 + d];
    __syncthreads();
    float acc = 0.f;
#pragma unroll
    for (int i = 0; i < 32; ++i) acc += xs[i] * w[i * D_MODEL + d];
    acc = (acc + b[d]) * 16.0f;     // sqrt(256)
    int m = d >> 1;
    float div = expf(-(float)(2 * m) * (9.210340371976184f / 256.0f)); // ln(1e4)/256
    float ang = (float)l * div;
    float pe = (d & 1) ? cosf(ang) : sinf(ang);
    h[row * D_MODEL + d] = acc + pe;
}

// ---------------------------------------------------------------------------
// Shared fp32 tiled GEMM body: C[64x64 tile] = A[M,K(lda)] @ W[K,N] (+ bias)
// MODE 0: plain   MODE 1: relu   MODE 2: scatter to q/k/v layout [B,H,L,32]
// ---------------------------------------------------------------------------
template <int MODE>
__device__ __forceinline__ void gemm_body(const float* __restrict__ A, int lda,
                                          const float* __restrict__ W, int N,
                                          const float* __restrict__ bias, bool doBias,
                                          float* __restrict__ C, int K,
                                          int m0, int n0) {
    __shared__ float As[16][68];
    __shared__ float Ws[16][68];
    const int t  = threadIdx.x;
    const int tx = t & 15, ty = t >> 4;
    float acc[4][4] = {};
    for (int k0 = 0; k0 < K; k0 += 16) {
        {
            int mr = t >> 2, kc = (t & 3) * 4;
            float4 av = *(const float4*)&A[(size_t)(m0 + mr) * lda + k0 + kc];
            As[kc + 0][mr] = av.x; As[kc + 1][mr] = av.y;
            As[kc + 2][mr] = av.z; As[kc + 3][mr] = av.w;
            int kr = t >> 4, nc = (t & 15) * 4;
            *(float4*)&Ws[kr][nc] = *(const float4*)&W[(size_t)(k0 + kr) * N + n0 + nc];
        }
        __syncthreads();
#pragma unroll
        for (int k = 0; k < 16; ++k) {
            float4 a4 = *(const float4*)&As[k][ty * 4];
            float4 w4 = *(const float4*)&Ws[k][tx * 4];
            float av[4] = {a4.x, a4.y, a4.z, a4.w};
            float wv[4] = {w4.x, w4.y, w4.z, w4.w};
#pragma unroll
            for (int i = 0; i < 4; ++i)
#pragma unroll
                for (int j = 0; j < 4; ++j) acc[i][j] += av[i] * wv[j];
        }
        __syncthreads();
    }
#pragma unroll
    for (int i = 0; i < 4; ++i) {
        int row = m0 + ty * 4 + i;
#pragma unroll
        for (int j = 0; j < 4; ++j) {
            int col = n0 + tx * 4 + j;
            float v = acc[i][j];
            if (doBias) v += bias[col];
            if (MODE == 1) v = fmaxf(v, 0.f);
            if (MODE == 2) {
                int bb = row >> 11, ll = row & (LSEQ - 1);
                int hh = col >> 5, dd = col & 31;
                C[(((size_t)(bb * NHEAD + hh) * LSEQ) + ll) * D_K + dd] = v;
            } else {
                C[(size_t)row * N + col] = v;
            }
        }
    }
}

// QKV fused: blockIdx.z selects {wq,wk,wv}; scatters to [B,H,L,32] at out+z*1M.
__global__ __launch_bounds__(256) void k_qkv(const float* __restrict__ A,
                                             const float* __restrict__ wq,
                                             const float* __restrict__ wk,
                                             const float* __restrict__ wv,
                                             const float* __restrict__ bq,
                                             const float* __restrict__ bk,
                                             const float* __restrict__ bv,
                                             float* __restrict__ out) {
    int z = blockIdx.z;
    const float* W = z == 0 ? wq : (z == 1 ? wk : wv);
    const float* B = z == 0 ? bq : (z == 1 ? bk : bv);
    gemm_body<2>(A, 256, W, 256, B, true, out + (size_t)z * (1 << 20), 256,
                 blockIdx.x * 64, blockIdx.y * 64);
}

// split-K GEMM: blockIdx.z = K-half; partial z to Cbase + z*1M; bias on z=0 only.
__global__ __launch_bounds__(256) void k_gemm_sk(const float* __restrict__ A, int lda,
                                                 const float* __restrict__ W,
                                                 const float* __restrict__ bias,
                                                 float* __restrict__ Cbase,
                                                 int N, int Ksub) {
    int z = blockIdx.z;
    gemm_body<0>(A + (size_t)z * Ksub, lda, W + (size_t)z * Ksub * N, N, bias, z == 0,
                 Cbase + (size_t)z * (1 << 20), Ksub, blockIdx.x * 64, blockIdx.y * 64);
}

// ff1: relu GEMM, N=1024
__global__ __launch_bounds__(256) void k_ff1(const float* __restrict__ A,
                                             const float* __restrict__ W,
                                             const float* __restrict__ bias,
                                             float* __restrict__ C) {
    gemm_body<1>(A, 256, W, 1024, bias, true, C, 256, blockIdx.x * 64, blockIdx.y * 64);
}

// ---------------------------------------------------------------------------
// Fused ProbSparse attention v9 — pivot select; 2 rows/wave full-dim lanes;
// XOR-swizzled K tiles (both-sides: inverse-permuted gload source + swizzled
// read); triple-buffered staging with counted vmcnt(2) + raw s_barrier
// (loads stay in flight across barriers). Algorithm identical to verified
// v6-v8: two QK passes, pivot = 38th of 64 lane-maxes (bitonic), candidate
// push >= pivot, exact 4-bit radix threshold, softmax + PV gather.
// ---------------------------------------------------------------------------
__device__ __forceinline__ unsigned int sortkey(float f) {
    unsigned int u = __float_as_uint(f);
    return (u & 0x80000000u) ? ~u : (u | 0x80000000u);
}
__device__ __forceinline__ float key2f(unsigned int u) {
    unsigned int b = (u & 0x80000000u) ? (u ^ 0x80000000u) : ~u;
    return __uint_as_float(b);
}
__device__ __forceinline__ void gload_lds16(const float* src, float* ldsDst) {
    __builtin_amdgcn_global_load_lds(
        (const __attribute__((address_space(1))) unsigned int*)src,
        (__attribute__((address_space(3))) unsigned int*)ldsDst,
        16, 0, 0);
}

__global__ __launch_bounds__(256, 4) void k_attn(const float* __restrict__ Q,
                                                 const float* __restrict__ Kt,
                                                 const float* __restrict__ Vt,
                                                 float* __restrict__ ctxb) {
    __shared__ float          Kl[3][2048];      // 24 KB  K tile triple-buffer
    __shared__ unsigned int   lvk[4][2][CAP];   // 4 KB   candidate keys
    __shared__ unsigned short lix[4][2][CAP];   // 2 KB   candidate indices
    __shared__ int            bins[4][16];      // 256 B
    __shared__ int            lcnt[4][2];

    const int tid   = threadIdx.x;
    const int lane  = tid & 63;
    const int wid   = tid >> 6;
    // XCD swizzle: grid 4096 = 8 XCDs x 512 (bijective).
    const int lbid  = (blockIdx.x & 7) * 512 + (blockIdx.x >> 3);
    const int bh    = lbid >> 8;                // 16 bh x 256 chunks
    const int chunk = lbid & 255;
    const int row0  = chunk * 8 + wid * 2;      // 2 rows per wave
    const int b     = bh >> 3, hh = bh & 7;
    const int sw    = lane & 7;                 // read-swizzle class

    const float* Kb = Kt + (size_t)bh * LSEQ * D_K;
    const float* Vb = Vt + (size_t)bh * LSEQ * D_K;
    const float* qp = Q + ((size_t)bh * LSEQ + row0) * D_K;

    const float scale = 0.17677669529663687f;   // 1/sqrt(32)
    float q0[32], q1[32];
#pragma unroll
    for (int i = 0; i < 32; ++i) {
        q0[i] = qp[i] * scale;
        q1[i] = qp[32 + i] * scale;
    }

    // staging: granule G in [0,512) holds K[key=G>>3][dims 4*((G&7)^((G>>3)&7))..+4)
    // at LDS byte G*16 (linear dest). Thread stages G=tid and G=tid+256.
    const int g1 = tid, g2 = tid + 256;
    const int k1o = (g1 >> 3) * 32 + 4 * ((g1 & 7) ^ ((g1 >> 3) & 7));
    const int k2o = (g2 >> 3) * 32 + 4 * ((g2 & 7) ^ ((g2 >> 3) & 7));

#define STAGE(T, SLOT)                                                     \
    {                                                                      \
        gload_lds16(Kb + (size_t)(T) * 2048 + k1o, &Kl[SLOT][g1 * 4]);     \
        gload_lds16(Kb + (size_t)(T) * 2048 + k2o, &Kl[SLOT][g2 * 4]);     \
    }

    // ================= PASS 1: dots, lane-max per row ====================
    unsigned int lm0 = 0u, lm1 = 0u;
    STAGE(0, 0)
    STAGE(1, 1)
    asm volatile("s_waitcnt vmcnt(2)" ::: "memory");
    __builtin_amdgcn_s_barrier();

    {
        int slot = 0, s2 = 2;
        for (int t = 0; t < 32; ++t) {
            if (t + 2 < 32) STAGE(t + 2, s2)
            float a0 = 0.f, a1 = 0.f;
#pragma unroll
            for (int u = 0; u < 8; ++u) {
                float4 kv = *(const float4*)&Kl[slot][lane * 32 + 4 * (u ^ sw)];
                a0 += q0[u*4+0]*kv.x + q0[u*4+1]*kv.y + q0[u*4+2]*kv.z + q0[u*4+3]*kv.w;
                a1 += q1[u*4+0]*kv.x + q1[u*4+1]*kv.y + q1[u*4+2]*kv.z + q1[u*4+3]*kv.w;
            }
            unsigned int s0 = sortkey(a0), s1k = sortkey(a1);
            if (s0 > lm0) lm0 = s0;
            if (s1k > lm1) lm1 = s1k;
            if (t < 31) {
                if (t + 2 < 32) asm volatile("s_waitcnt vmcnt(2)" ::: "memory");
                else            asm volatile("s_waitcnt vmcnt(0)" ::: "memory");
                __builtin_amdgcn_s_barrier();
            }
            slot = (slot == 2) ? 0 : slot + 1;
            s2   = (s2   == 2) ? 0 : s2   + 1;
        }
    }

    // ---- pivot per row: bitonic-sort 64 lane-maxes, broadcast via shfl --
    unsigned int Tpiv[2];
    float        rmaxf[2];
#pragma unroll
    for (int r = 0; r < 2; ++r) {
        unsigned int v = r ? lm1 : lm0;
#pragma unroll
        for (int k = 2; k <= 64; k <<= 1) {
#pragma unroll
            for (int j = k >> 1; j >= 1; j >>= 1) {
                unsigned int pv = (unsigned int)__shfl_xor((int)v, j);
                bool lower = ((lane & j) == 0);
                bool up    = ((lane & k) == 0);
                unsigned int mn = v < pv ? v : pv;
                unsigned int mx = v < pv ? pv : v;
                v = (lower == up) ? mn : mx;
            }
        }
        Tpiv[r]  = (unsigned int)__shfl((int)v, 26);  // 38th-largest lane-max
        rmaxf[r] = key2f((unsigned int)__shfl((int)v, 63));
    }
    if (lane < 2) lcnt[wid][lane] = 0;
    __syncthreads();   // all waves done with Kl before pass-2 restaging

    // ================= PASS 2: recompute, push candidates ================
    STAGE(0, 0)
    STAGE(1, 1)
    asm volatile("s_waitcnt vmcnt(2)" ::: "memory");
    __builtin_amdgcn_s_barrier();

    {
        int slot = 0, s2 = 2;
        for (int t = 0; t < 32; ++t) {
            if (t + 2 < 32) STAGE(t + 2, s2)
            float a0 = 0.f, a1 = 0.f;
#pragma unroll
            for (int u = 0; u < 8; ++u) {
                float4 kv = *(const float4*)&Kl[slot][lane * 32 + 4 * (u ^ sw)];
                a0 += q0[u*4+0]*kv.x + q0[u*4+1]*kv.y + q0[u*4+2]*kv.z + q0[u*4+3]*kv.w;
                a1 += q1[u*4+0]*kv.x + q1[u*4+1]*kv.y + q1[u*4+2]*kv.z + q1[u*4+3]*kv.w;
            }
            unsigned int s0 = sortkey(a0), s1k = sortkey(a1);
            const int kidx = t * 64 + lane;
            if (s0 >= Tpiv[0]) {
                int slotc = atomicAdd(&lcnt[wid][0], 1);
                if (slotc < CAP) { lvk[wid][0][slotc] = s0; lix[wid][0][slotc] = (unsigned short)kidx; }
            }
            if (s1k >= Tpiv[1]) {
                int slotc = atomicAdd(&lcnt[wid][1], 1);
                if (slotc < CAP) { lvk[wid][1][slotc] = s1k; lix[wid][1][slotc] = (unsigned short)kidx; }
            }
            if (t < 31) {
                if (t + 2 < 32) asm volatile("s_waitcnt vmcnt(2)" ::: "memory");
                else            asm volatile("s_waitcnt vmcnt(0)" ::: "memory");
                __builtin_amdgcn_s_barrier();
            }
            slot = (slot == 2) ? 0 : slot + 1;
            s2   = (s2   == 2) ? 0 : s2   + 1;
        }
    }

    // ---- per-row: exact 4-bit radix select, softmax, PV ----------------
    const int h  = lane >> 5;
    const int p  = lane & 31;
    for (int r = 0; r < 2; ++r) {
        int cnt = lcnt[wid][r]; if (cnt > CAP) cnt = CAP;

        unsigned int prefix = 0;
        int need = UTOP;
#pragma unroll
        for (int pass = 0; pass < 8; ++pass) {
            const int sh = 28 - pass * 4;
            if (lane < 16) bins[wid][lane] = 0;
            for (int i = lane; i < cnt; i += 64) {
                unsigned int key = lvk[wid][r][i];
                bool msk = (pass == 0) || ((key >> (sh + 4)) == (prefix >> (sh + 4)));
                if (msk) atomicAdd(&bins[wid][(key >> sh) & 15], 1);
            }
            int c = (lane < 16) ? bins[wid][lane] : 0;
            int suf = c;
#pragma unroll
            for (int off = 1; off < 16; off <<= 1) {
                int o = __shfl_down(suf, off);
                suf += (lane + off < 16) ? o : 0;
            }
            int above = suf - c;    // count in strictly-higher bins
            bool found = (lane < 16) && (above < need) && (above + c >= need);
            unsigned int cp = prefix | ((unsigned int)lane << sh);
            int cn = need - above;
            unsigned long long bal = __ballot(found);
            int wl = (int)(__ffsll(bal) - 1);
            prefix = (unsigned int)__shfl((int)cp, wl);
            need   = __shfl(cn, wl);
        }
        const unsigned int thrkey = prefix;   // exact 38th-largest key

        float psum = 0.f;
        for (int i = lane; i < cnt; i += 64) {
            unsigned int key = lvk[wid][r][i];
            if (key >= thrkey) psum += expf(key2f(key) - rmaxf[r]);
        }
#pragma unroll
        for (int off = 32; off >= 1; off >>= 1) psum += __shfl_xor(psum, off);
        float inv = 1.0f / psum;

        float acc = 0.f;
        for (int i = h; i < cnt; i += 2) {
            unsigned int key = lvk[wid][r][i];
            float w = (key >= thrkey) ? expf(key2f(key) - rmaxf[r]) : 0.f;
            acc += w * Vb[(size_t)lix[wid][r][i] * D_K + p];
        }
        acc += __shfl_xor(acc, 32);
        if (lane < 32)
            ctxb[((size_t)(b * LSEQ) + row0 + r) * D_MODEL + hh * D_K + p] = acc * inv;
    }
}

// ---------------------------------------------------------------------------
// Residual add (two partials) + LayerNorm over 256, in place into h.
// ---------------------------------------------------------------------------
__global__ __launch_bounds__(64) void k_addln2(float* __restrict__ h,
                                               const float* __restrict__ a1,
                                               const float* __restrict__ a2,
                                               const float* __restrict__ g,
                                               const float* __restrict__ bb) {
    int row = blockIdx.x, lane = threadIdx.x;
    float4 hv = *(const float4*)&h[(size_t)row * D_MODEL + lane * 4];
    float4 v1 = *(const float4*)&a1[(size_t)row * D_MODEL + lane * 4];
    float4 v2 = *(const float4*)&a2[(size_t)row * D_MODEL + lane * 4];
    float x0 = hv.x + v1.x + v2.x, x1 = hv.y + v1.y + v2.y;
    float x2 = hv.z + v1.z + v2.z, x3 = hv.w + v1.w + v2.w;
    float s = x0 + x1 + x2 + x3;
#pragma unroll
    for (int off = 32; off >= 1; off >>= 1) s += __shfl_xor(s, off);
    float mean = s * (1.0f / 256.0f);
    float d0 = x0 - mean, d1 = x1 - mean, d2 = x2 - mean, d3 = x3 - mean;
    float vs = d0 * d0 + d1 * d1 + d2 * d2 + d3 * d3;
#pragma unroll
    for (int off = 32; off >= 1; off >>= 1) vs += __shfl_xor(vs, off);
    float inv = rsqrtf(vs * (1.0f / 256.0f) + 1e-5f);
    float4 gv = *(const float4*)&g[lane * 4];
    float4 bv = *(const float4*)&bb[lane * 4];
    float4 o;
    o.x = d0 * inv * gv.x + bv.x;
    o.y = d1 * inv * gv.y + bv.y;
    o.z = d2 * inv * gv.z + bv.z;
    o.w = d3 * inv * gv.w + bv.w;
    *(float4*)&h[(size_t)row * D_MODEL + lane * 4] = o;
}

// ---------------------------------------------------------------------------
// Decoder head
// ---------------------------------------------------------------------------
__global__ __launch_bounds__(64) void k_dec(const float* __restrict__ h,
                                            const float* __restrict__ w,
                                            const float* __restrict__ b,
                                            float* __restrict__ out) {
    int row = blockIdx.x, lane = threadIdx.x;
    int c = lane & 7, part = lane >> 3;   // 8 parts x 32 dims
    float acc = 0.f;
    int d0 = part * 32;
#pragma unroll
    for (int dd = 0; dd < 32; ++dd) acc += h[(size_t)row * D_MODEL + d0 + dd] * w[(d0 + dd) * 8 + c];
    acc += __shfl_xor(acc, 8);
    acc += __shfl_xor(acc, 16);
    acc += __shfl_xor(acc, 32);
    if (lane < 8) out[(size_t)row * 8 + c] = acc + b[c];
}

// ---------------------------------------------------------------------------
extern "C" void kernel_launch(void* const* d_in, const int* in_sizes, int n_in,
                              void* d_out, int out_size, void* d_ws, size_t ws_size,
                              hipStream_t stream) {
    const float* x     = (const float*)d_in[0];
    const float* emb_w = (const float*)d_in[1];
    const float* emb_b = (const float*)d_in[2];
    const float* wq    = (const float*)d_in[3];
    const float* bq    = (const float*)d_in[4];
    const float* wk    = (const float*)d_in[5];
    const float* bk    = (const float*)d_in[6];
    const float* wv    = (const float*)d_in[7];
    const float* bv    = (const float*)d_in[8];
    const float* wo    = (const float*)d_in[9];
    const float* bo    = (const float*)d_in[10];
    const float* ln1_g = (const float*)d_in[11];
    const float* ln1_b = (const float*)d_in[12];
    const float* ln2_g = (const float*)d_in[13];
    const float* ln2_b = (const float*)d_in[14];
    const float* ff1_w = (const float*)d_in[15];
    const float* ff1_b = (const float*)d_in[16];
    const float* ff2_w = (const float*)d_in[17];
    const float* ff2_b = (const float*)d_in[18];
    const float* dec_w = (const float*)d_in[19];
    const float* dec_b = (const float*)d_in[20];

    float* ws   = (float*)d_ws;
    float* h    = ws;                      // 4096*256   = 1M floats
    float* qb   = h    + (1 << 20);        // qb/kb/vb: [B,H,L,32] each 1M
    float* kb   = qb   + (1 << 20);
    float* vb   = kb   + (1 << 20);
    float* ctxb = vb   + (1 << 20);
    float* ffb  = ctxb + (1 << 20);        // 4096*1024 = 4M

    k_embed<<<ROWS, 256, 0, stream>>>(x, emb_w, emb_b, h);

    for (int l = 0; l < 2; ++l) {
        const float* wql = wq + (size_t)l * 65536;  const float* bql = bq + l * 256;
        const float* wkl = wk + (size_t)l * 65536;  const float* bkl = bk + l * 256;
        const float* wvl = wv + (size_t)l * 65536;  const float* bvl = bv + l * 256;
        const float* wol = wo + (size_t)l * 65536;  const float* bol = bo + l * 256;

        dim3 gq(64, 4, 3);
        k_qkv<<<gq, 256, 0, stream>>>(h, wql, wkl, wvl, bql, bkl, bvl, qb);

        k_attn<<<NHEAD * BATCH * 256, 256, 0, stream>>>(qb, kb, vb, ctxb);

        // wo: split-K (128 x 2) -> partials in qb, kb (free after attn)
        dim3 gsk(64, 4, 2);
        k_gemm_sk<<<gsk, 256, 0, stream>>>(ctxb, 256, wol, bol, qb, 256, 128);
        k_addln2<<<ROWS, 64, 0, stream>>>(h, qb, kb, ln1_g + l * 256, ln1_b + l * 256);

        dim3 gf1(64, 16);
        k_ff1<<<gf1, 256, 0, stream>>>(h, ff1_w + (size_t)l * 262144, ff1_b + l * 1024, ffb);

        // ff2: split-K (512 x 2) -> partials in qb, kb
        k_gemm_sk<<<gsk, 256, 0, stream>>>(ffb, 1024, ff2_w + (size_t)l * 262144,
                                           ff2_b + l * 256, qb, 256, 512);
        k_addln2<<<ROWS, 64, 0, stream>>>(h, qb, kb, ln2_g + l * 256, ln2_b + l * 256);
    }

    k_dec<<<ROWS, 64, 0, stream>>>(h, dec_w, dec_b, (float*)d_out);
}

// Round 13
// 868.085 us; speedup vs baseline: 2.0721x; 1.1018x over previous
//
#include <hip/hip_runtime.h>
#include <math.h>

#define D_MODEL 256
#define NHEAD   8
#define D_K     32
#define LSEQ    2048
#define BATCH   2
#define ROWS    (BATCH * LSEQ)   // 4096
#define D_FF    1024
#define UTOP    38
#define CAP     128

// ---------------------------------------------------------------------------
// Embedding + positional encoding
// ---------------------------------------------------------------------------
__global__ __launch_bounds__(256) void k_embed(const float* __restrict__ x,
                                               const float* __restrict__ w,
                                               const float* __restrict__ b,
                                               float* __restrict__ h) {
    int row = blockIdx.x;           // b*L + l
    int l   = row & (LSEQ - 1);
    int d   = threadIdx.x;
    __shared__ float xs[32];
    if (d < 32) xs[d] = x[row * 32 + d];
    __syncthreads();
    float acc = 0.f;
#pragma unroll
    for (int i = 0; i < 32; ++i) acc += xs[i] * w[i * D_MODEL + d];
    acc = (acc + b[d]) * 16.0f;     // sqrt(256)
    int m = d >> 1;
    float div = expf(-(float)(2 * m) * (9.210340371976184f / 256.0f)); // ln(1e4)/256
    float ang = (float)l * div;
    float pe = (d & 1) ? cosf(ang) : sinf(ang);
    h[row * D_MODEL + d] = acc + pe;
}

// ---------------------------------------------------------------------------
// Shared fp32 tiled GEMM body: C[64x64 tile] = A[M,K(lda)] @ W[K,N] (+ bias)
// MODE 0: plain   MODE 1: relu   MODE 2: scatter to q/k/v layout [B,H,L,32]
// ---------------------------------------------------------------------------
template <int MODE>
__device__ __forceinline__ void gemm_body(const float* __restrict__ A, int lda,
                                          const float* __restrict__ W, int N,
                                          const float* __restrict__ bias, bool doBias,
                                          float* __restrict__ C, int K,
                                          int m0, int n0) {
    __shared__ float As[16][68];
    __shared__ float Ws[16][68];
    const int t  = threadIdx.x;
    const int tx = t & 15, ty = t >> 4;
    float acc[4][4] = {};
    for (int k0 = 0; k0 < K; k0 += 16) {
        {
            int mr = t >> 2, kc = (t & 3) * 4;
            float4 av = *(const float4*)&A[(size_t)(m0 + mr) * lda + k0 + kc];
            As[kc + 0][mr] = av.x; As[kc + 1][mr] = av.y;
            As[kc + 2][mr] = av.z; As[kc + 3][mr] = av.w;
            int kr = t >> 4, nc = (t & 15) * 4;
            *(float4*)&Ws[kr][nc] = *(const float4*)&W[(size_t)(k0 + kr) * N + n0 + nc];
        }
        __syncthreads();
#pragma unroll
        for (int k = 0; k < 16; ++k) {
            float4 a4 = *(const float4*)&As[k][ty * 4];
            float4 w4 = *(const float4*)&Ws[k][tx * 4];
            float av[4] = {a4.x, a4.y, a4.z, a4.w};
            float wv[4] = {w4.x, w4.y, w4.z, w4.w};
#pragma unroll
            for (int i = 0; i < 4; ++i)
#pragma unroll
                for (int j = 0; j < 4; ++j) acc[i][j] += av[i] * wv[j];
        }
        __syncthreads();
    }
#pragma unroll
    for (int i = 0; i < 4; ++i) {
        int row = m0 + ty * 4 + i;
#pragma unroll
        for (int j = 0; j < 4; ++j) {
            int col = n0 + tx * 4 + j;
            float v = acc[i][j];
            if (doBias) v += bias[col];
            if (MODE == 1) v = fmaxf(v, 0.f);
            if (MODE == 2) {
                int bb = row >> 11, ll = row & (LSEQ - 1);
                int hh = col >> 5, dd = col & 31;
                C[(((size_t)(bb * NHEAD + hh) * LSEQ) + ll) * D_K + dd] = v;
            } else {
                C[(size_t)row * N + col] = v;
            }
        }
    }
}

// QKV fused: blockIdx.z selects {wq,wk,wv}; scatters to [B,H,L,32] at out+z*1M.
__global__ __launch_bounds__(256) void k_qkv(const float* __restrict__ A,
                                             const float* __restrict__ wq,
                                             const float* __restrict__ wk,
                                             const float* __restrict__ wv,
                                             const float* __restrict__ bq,
                                             const float* __restrict__ bk,
                                             const float* __restrict__ bv,
                                             float* __restrict__ out) {
    int z = blockIdx.z;
    const float* W = z == 0 ? wq : (z == 1 ? wk : wv);
    const float* B = z == 0 ? bq : (z == 1 ? bk : bv);
    gemm_body<2>(A, 256, W, 256, B, true, out + (size_t)z * (1 << 20), 256,
                 blockIdx.x * 64, blockIdx.y * 64);
}

// split-K GEMM: blockIdx.z = K-half; partial z to Cbase + z*1M; bias on z=0 only.
__global__ __launch_bounds__(256) void k_gemm_sk(const float* __restrict__ A, int lda,
                                                 const float* __restrict__ W,
                                                 const float* __restrict__ bias,
                                                 float* __restrict__ Cbase,
                                                 int N, int Ksub) {
    int z = blockIdx.z;
    gemm_body<0>(A + (size_t)z * Ksub, lda, W + (size_t)z * Ksub * N, N, bias, z == 0,
                 Cbase + (size_t)z * (1 << 20), Ksub, blockIdx.x * 64, blockIdx.y * 64);
}

// ff1: relu GEMM, N=1024
__global__ __launch_bounds__(256) void k_ff1(const float* __restrict__ A,
                                             const float* __restrict__ W,
                                             const float* __restrict__ bias,
                                             float* __restrict__ C) {
    gemm_body<1>(A, 256, W, 1024, bias, true, C, 256, blockIdx.x * 64, blockIdx.y * 64);
}

// ---------------------------------------------------------------------------
// Fused ProbSparse attention v10 — SINGLE pass, scores in registers.
// 2 rows/wave, lane owns key = lane of each 64-key tile.
// LDS layout chunk-major: granule row u (u=0..7) holds dim-chunk u of all 64
// keys, key-major by lane -> read Kl[u*256 + lane*4] is the lane-consecutive
// conflict-floor pattern (R11-verified ~1.1 conflict-cyc/read; the R12 XOR
// swizzle measured 4.6). Staging source is the permuted side (per-lane
// Kb + lane*32 + u*4). Phase loop FULLY UNROLLED so k0[t]/k1[t] are
// static-indexed -> VGPRs, no scratch (rule #20; R5 lesson).
// Pivot = 38th of 64 lane-maxes (bitonic), push >= pivot FROM REGISTERS,
// exact 4-bit radix threshold over list, softmax + PV. No pass 2.
// __launch_bounds__(256,3): ~155 VGPR live < 170 budget (R10 rule).
// ---------------------------------------------------------------------------
__device__ __forceinline__ unsigned int sortkey(float f) {
    unsigned int u = __float_as_uint(f);
    return (u & 0x80000000u) ? ~u : (u | 0x80000000u);
}
__device__ __forceinline__ float key2f(unsigned int u) {
    unsigned int b = (u & 0x80000000u) ? (u ^ 0x80000000u) : ~u;
    return __uint_as_float(b);
}
__device__ __forceinline__ void gload_lds16(const float* src, float* ldsDst) {
    __builtin_amdgcn_global_load_lds(
        (const __attribute__((address_space(1))) unsigned int*)src,
        (__attribute__((address_space(3))) unsigned int*)ldsDst,
        16, 0, 0);
}

__global__ __launch_bounds__(256, 3) void k_attn(const float* __restrict__ Q,
                                                 const float* __restrict__ Kt,
                                                 const float* __restrict__ Vt,
                                                 float* __restrict__ ctxb) {
    __shared__ float          Kl[3][2048];      // 24 KB  K tile triple-buffer
    __shared__ unsigned int   lvk[4][2][CAP];   // 4 KB   candidate keys
    __shared__ unsigned short lix[4][2][CAP];   // 2 KB   candidate indices
    __shared__ int            bins[4][16];      // 256 B
    __shared__ int            lcnt[4][2];

    const int tid   = threadIdx.x;
    const int lane  = tid & 63;
    const int wid   = tid >> 6;
    // XCD swizzle: grid 4096 = 8 XCDs x 512 (bijective).
    const int lbid  = (blockIdx.x & 7) * 512 + (blockIdx.x >> 3);
    const int bh    = lbid >> 8;                // 16 bh x 256 chunks
    const int chunk = lbid & 255;
    const int row0  = chunk * 8 + wid * 2;      // 2 rows per wave
    const int b     = bh >> 3, hh = bh & 7;

    const float* Kb = Kt + (size_t)bh * LSEQ * D_K;
    const float* Vb = Vt + (size_t)bh * LSEQ * D_K;
    const float* qp = Q + ((size_t)bh * LSEQ + row0) * D_K;

    const float scale = 0.17677669529663687f;   // 1/sqrt(32)
    float q0[32], q1[32];
#pragma unroll
    for (int i = 0; i < 32; ++i) {
        q0[i] = qp[i] * scale;
        q1[i] = qp[32 + i] * scale;
    }

    // Stage tile T into slot: wave wid stages granule rows g = wid*2+{0,1}.
    // Granule row g = dim-chunk g of all 64 keys; lane l supplies key l:
    //   src = Kb + T*2048 + l*32 + g*4 (16B), dst = Kl[slot] + g*1024B + l*16B.
#define STAGE(T, SLOT)                                                          \
    {                                                                           \
        int g0_ = wid * 2, g1_ = wid * 2 + 1;                                   \
        gload_lds16(Kb + (size_t)(T) * 2048 + lane * 32 + g0_ * 4,              \
                    &Kl[SLOT][g0_ * 256]);                                      \
        gload_lds16(Kb + (size_t)(T) * 2048 + lane * 32 + g1_ * 4,              \
                    &Kl[SLOT][g1_ * 256]);                                      \
    }

    // ---- single pass: dots -> registers, track lane-max ----------------
    unsigned int k0[32], k1[32];
    unsigned int lm0 = 0u, lm1 = 0u;

    STAGE(0, 0)
    STAGE(1, 1)
    asm volatile("s_waitcnt vmcnt(2)" ::: "memory");
    __builtin_amdgcn_s_barrier();

#pragma unroll
    for (int t = 0; t < 32; ++t) {
        const int slot = t % 3;               // literal under full unroll
        if (t < 30) STAGE(t + 2, (t + 2) % 3)
        float a0 = 0.f, a1 = 0.f;
#pragma unroll
        for (int u = 0; u < 8; ++u) {
            float4 kv = *(const float4*)&Kl[slot][u * 256 + lane * 4];
            a0 += q0[u*4+0]*kv.x + q0[u*4+1]*kv.y + q0[u*4+2]*kv.z + q0[u*4+3]*kv.w;
            a1 += q1[u*4+0]*kv.x + q1[u*4+1]*kv.y + q1[u*4+2]*kv.z + q1[u*4+3]*kv.w;
        }
        k0[t] = sortkey(a0);
        k1[t] = sortkey(a1);
        if (k0[t] > lm0) lm0 = k0[t];
        if (k1[t] > lm1) lm1 = k1[t];
        if (t < 31) {
            if (t < 30) asm volatile("s_waitcnt vmcnt(2)" ::: "memory");
            else        asm volatile("s_waitcnt vmcnt(0)" ::: "memory");
            __builtin_amdgcn_s_barrier();
        }
    }

    // ---- pivot per row: bitonic-sort 64 lane-maxes, broadcast via shfl --
    unsigned int Tpiv[2];
    float        rmaxf[2];
#pragma unroll
    for (int r = 0; r < 2; ++r) {
        unsigned int v = r ? lm1 : lm0;
#pragma unroll
        for (int k = 2; k <= 64; k <<= 1) {
#pragma unroll
            for (int j = k >> 1; j >= 1; j >>= 1) {
                unsigned int pv = (unsigned int)__shfl_xor((int)v, j);
                bool lower = ((lane & j) == 0);
                bool up    = ((lane & k) == 0);
                unsigned int mn = v < pv ? v : pv;
                unsigned int mx = v < pv ? pv : v;
                v = (lower == up) ? mn : mx;
            }
        }
        Tpiv[r]  = (unsigned int)__shfl((int)v, 26);  // 38th-largest lane-max
        rmaxf[r] = key2f((unsigned int)__shfl((int)v, 63));
    }
    if (lane < 2) lcnt[wid][lane] = 0;

    // ---- push candidates >= pivot from registers -----------------------
#pragma unroll
    for (int j = 0; j < 32; ++j) {
        if (k0[j] >= Tpiv[0]) {
            int s = atomicAdd(&lcnt[wid][0], 1);
            if (s < CAP) { lvk[wid][0][s] = k0[j]; lix[wid][0][s] = (unsigned short)(j * 64 + lane); }
        }
        if (k1[j] >= Tpiv[1]) {
            int s = atomicAdd(&lcnt[wid][1], 1);
            if (s < CAP) { lvk[wid][1][s] = k1[j]; lix[wid][1][s] = (unsigned short)(j * 64 + lane); }
        }
    }

    // ---- per-row: exact 4-bit radix select, softmax, PV ----------------
    const int h = lane >> 5;
    const int p = lane & 31;
#pragma unroll
    for (int r = 0; r < 2; ++r) {
        int cnt = lcnt[wid][r]; if (cnt > CAP) cnt = CAP;

        unsigned int prefix = 0;
        int need = UTOP;
#pragma unroll
        for (int pass = 0; pass < 8; ++pass) {
            const int sh = 28 - pass * 4;
            if (lane < 16) bins[wid][lane] = 0;
            for (int i = lane; i < cnt; i += 64) {
                unsigned int key = lvk[wid][r][i];
                bool msk = (pass == 0) || ((key >> (sh + 4)) == (prefix >> (sh + 4)));
                if (msk) atomicAdd(&bins[wid][(key >> sh) & 15], 1);
            }
            int c = (lane < 16) ? bins[wid][lane] : 0;
            int suf = c;
#pragma unroll
            for (int off = 1; off < 16; off <<= 1) {
                int o = __shfl_down(suf, off);
                suf += (lane + off < 16) ? o : 0;
            }
            int above = suf - c;    // count in strictly-higher bins
            bool found = (lane < 16) && (above < need) && (above + c >= need);
            unsigned int cp = prefix | ((unsigned int)lane << sh);
            int cn = need - above;
            unsigned long long bal = __ballot(found);
            int wl = (int)(__ffsll(bal) - 1);
            prefix = (unsigned int)__shfl((int)cp, wl);
            need   = __shfl(cn, wl);
        }
        const unsigned int thrkey = prefix;   // exact 38th-largest key

        float psum = 0.f;
        for (int i = lane; i < cnt; i += 64) {
            unsigned int key = lvk[wid][r][i];
            if (key >= thrkey) psum += expf(key2f(key) - rmaxf[r]);
        }
#pragma unroll
        for (int off = 32; off >= 1; off >>= 1) psum += __shfl_xor(psum, off);
        float inv = 1.0f / psum;

        float acc = 0.f;
        for (int i = h; i < cnt; i += 2) {
            unsigned int key = lvk[wid][r][i];
            float w = (key >= thrkey) ? expf(key2f(key) - rmaxf[r]) : 0.f;
            acc += w * Vb[(size_t)lix[wid][r][i] * D_K + p];
        }
        acc += __shfl_xor(acc, 32);
        if (lane < 32)
            ctxb[((size_t)(b * LSEQ) + row0 + r) * D_MODEL + hh * D_K + p] = acc * inv;
    }
}

// ---------------------------------------------------------------------------
// Residual add (two partials) + LayerNorm over 256, in place into h.
// ---------------------------------------------------------------------------
__global__ __launch_bounds__(64) void k_addln2(float* __restrict__ h,
                                               const float* __restrict__ a1,
                                               const float* __restrict__ a2,
                                               const float* __restrict__ g,
                                               const float* __restrict__ bb) {
    int row = blockIdx.x, lane = threadIdx.x;
    float4 hv = *(const float4*)&h[(size_t)row * D_MODEL + lane * 4];
    float4 v1 = *(const float4*)&a1[(size_t)row * D_MODEL + lane * 4];
    float4 v2 = *(const float4*)&a2[(size_t)row * D_MODEL + lane * 4];
    float x0 = hv.x + v1.x + v2.x, x1 = hv.y + v1.y + v2.y;
    float x2 = hv.z + v1.z + v2.z, x3 = hv.w + v1.w + v2.w;
    float s = x0 + x1 + x2 + x3;
#pragma unroll
    for (int off = 32; off >= 1; off >>= 1) s += __shfl_xor(s, off);
    float mean = s * (1.0f / 256.0f);
    float d0 = x0 - mean, d1 = x1 - mean, d2 = x2 - mean, d3 = x3 - mean;
    float vs = d0 * d0 + d1 * d1 + d2 * d2 + d3 * d3;
#pragma unroll
    for (int off = 32; off >= 1; off >>= 1) vs += __shfl_xor(vs, off);
    float inv = rsqrtf(vs * (1.0f / 256.0f) + 1e-5f);
    float4 gv = *(const float4*)&g[lane * 4];
    float4 bv = *(const float4*)&bb[lane * 4];
    float4 o;
    o.x = d0 * inv * gv.x + bv.x;
    o.y = d1 * inv * gv.y + bv.y;
    o.z = d2 * inv * gv.z + bv.z;
    o.w = d3 * inv * gv.w + bv.w;
    *(float4*)&h[(size_t)row * D_MODEL + lane * 4] = o;
}

// ---------------------------------------------------------------------------
// Decoder head
// ---------------------------------------------------------------------------
__global__ __launch_bounds__(64) void k_dec(const float* __restrict__ h,
                                            const float* __restrict__ w,
                                            const float* __restrict__ b,
                                            float* __restrict__ out) {
    int row = blockIdx.x, lane = threadIdx.x;
    int c = lane & 7, part = lane >> 3;   // 8 parts x 32 dims
    float acc = 0.f;
    int d0 = part * 32;
#pragma unroll
    for (int dd = 0; dd < 32; ++dd) acc += h[(size_t)row * D_MODEL + d0 + dd] * w[(d0 + dd) * 8 + c];
    acc += __shfl_xor(acc, 8);
    acc += __shfl_xor(acc, 16);
    acc += __shfl_xor(acc, 32);
    if (lane < 8) out[(size_t)row * 8 + c] = acc + b[c];
}

// ---------------------------------------------------------------------------
extern "C" void kernel_launch(void* const* d_in, const int* in_sizes, int n_in,
                              void* d_out, int out_size, void* d_ws, size_t ws_size,
                              hipStream_t stream) {
    const float* x     = (const float*)d_in[0];
    const float* emb_w = (const float*)d_in[1];
    const float* emb_b = (const float*)d_in[2];
    const float* wq    = (const float*)d_in[3];
    const float* bq    = (const float*)d_in[4];
    const float* wk    = (const float*)d_in[5];
    const float* bk    = (const float*)d_in[6];
    const float* wv    = (const float*)d_in[7];
    const float* bv    = (const float*)d_in[8];
    const float* wo    = (const float*)d_in[9];
    const float* bo    = (const float*)d_in[10];
    const float* ln1_g = (const float*)d_in[11];
    const float* ln1_b = (const float*)d_in[12];
    const float* ln2_g = (const float*)d_in[13];
    const float* ln2_b = (const float*)d_in[14];
    const float* ff1_w = (const float*)d_in[15];
    const float* ff1_b = (const float*)d_in[16];
    const float* ff2_w = (const float*)d_in[17];
    const float* ff2_b = (const float*)d_in[18];
    const float* dec_w = (const float*)d_in[19];
    const float* dec_b = (const float*)d_in[20];

    float* ws   = (float*)d_ws;
    float* h    = ws;                      // 4096*256   = 1M floats
    float* qb   = h    + (1 << 20);        // qb/kb/vb: [B,H,L,32] each 1M
    float* kb   = qb   + (1 << 20);
    float* vb   = kb   + (1 << 20);
    float* ctxb = vb   + (1 << 20);
    float* ffb  = ctxb + (1 << 20);        // 4096*1024 = 4M

    k_embed<<<ROWS, 256, 0, stream>>>(x, emb_w, emb_b, h);

    for (int l = 0; l < 2; ++l) {
        const float* wql = wq + (size_t)l * 65536;  const float* bql = bq + l * 256;
        const float* wkl = wk + (size_t)l * 65536;  const float* bkl = bk + l * 256;
        const float* wvl = wv + (size_t)l * 65536;  const float* bvl = bv + l * 256;
        const float* wol = wo + (size_t)l * 65536;  const float* bol = bo + l * 256;

        dim3 gq(64, 4, 3);
        k_qkv<<<gq, 256, 0, stream>>>(h, wql, wkl, wvl, bql, bkl, bvl, qb);

        k_attn<<<NHEAD * BATCH * 256, 256, 0, stream>>>(qb, kb, vb, ctxb);

        // wo: split-K (128 x 2) -> partials in qb, kb (free after attn)
        dim3 gsk(64, 4, 2);
        k_gemm_sk<<<gsk, 256, 0, stream>>>(ctxb, 256, wol, bol, qb, 256, 128);
        k_addln2<<<ROWS, 64, 0, stream>>>(h, qb, kb, ln1_g + l * 256, ln1_b + l * 256);

        dim3 gf1(64, 16);
        k_ff1<<<gf1, 256, 0, stream>>>(h, ff1_w + (size_t)l * 262144, ff1_b + l * 1024, ffb);

        // ff2: split-K (512 x 2) -> partials in qb, kb
        k_gemm_sk<<<gsk, 256, 0, stream>>>(ffb, 1024, ff2_w + (size_t)l * 262144,
                                           ff2_b + l * 256, qb, 256, 512);
        k_addln2<<<ROWS, 64, 0, stream>>>(h, qb, kb, ln2_g + l * 256, ln2_b + l * 256);
    }

    k_dec<<<ROWS, 64, 0, stream>>>(h, dec_w, dec_b, (float*)d_out);
}

// Round 14
// 831.027 us; speedup vs baseline: 2.1645x; 1.0446x over previous
//
#include <hip/hip_runtime.h>
#include <math.h>

#define D_MODEL 256
#define NHEAD   8
#define D_K     32
#define LSEQ    2048
#define BATCH   2
#define ROWS    (BATCH * LSEQ)   // 4096
#define D_FF    1024
#define UTOP    38
#define CAP     128

// ---------------------------------------------------------------------------
// Embedding + positional encoding
// ---------------------------------------------------------------------------
__global__ __launch_bounds__(256) void k_embed(const float* __restrict__ x,
                                               const float* __restrict__ w,
                                               const float* __restrict__ b,
                                               float* __restrict__ h) {
    int row = blockIdx.x;           // b*L + l
    int l   = row & (LSEQ - 1);
    int d   = threadIdx.x;
    __shared__ float xs[32];
    if (d < 32) xs[d] = x[row * 32 + d];
    __syncthreads();
    float acc = 0.f;
#pragma unroll
    for (int i = 0; i < 32; ++i) acc += xs[i] * w[i * D_MODEL + d];
    acc = (acc + b[d]) * 16.0f;     // sqrt(256)
    int m = d >> 1;
    float div = expf(-(float)(2 * m) * (9.210340371976184f / 256.0f)); // ln(1e4)/256
    float ang = (float)l * div;
    float pe = (d & 1) ? cosf(ang) : sinf(ang);
    h[row * D_MODEL + d] = acc + pe;
}

// ---------------------------------------------------------------------------
// Shared fp32 tiled GEMM body: C[64x64 tile] = A[M,K(lda)] @ W[K,N] (+ bias)
// MODE 0: plain   MODE 1: relu   MODE 2: scatter to q/k/v layout [B,H,L,32]
// ---------------------------------------------------------------------------
template <int MODE>
__device__ __forceinline__ void gemm_body(const float* __restrict__ A, int lda,
                                          const float* __restrict__ W, int N,
                                          const float* __restrict__ bias, bool doBias,
                                          float* __restrict__ C, int K,
                                          int m0, int n0) {
    __shared__ float As[16][68];
    __shared__ float Ws[16][68];
    const int t  = threadIdx.x;
    const int tx = t & 15, ty = t >> 4;
    float acc[4][4] = {};
    for (int k0 = 0; k0 < K; k0 += 16) {
        {
            int mr = t >> 2, kc = (t & 3) * 4;
            float4 av = *(const float4*)&A[(size_t)(m0 + mr) * lda + k0 + kc];
            As[kc + 0][mr] = av.x; As[kc + 1][mr] = av.y;
            As[kc + 2][mr] = av.z; As[kc + 3][mr] = av.w;
            int kr = t >> 4, nc = (t & 15) * 4;
            *(float4*)&Ws[kr][nc] = *(const float4*)&W[(size_t)(k0 + kr) * N + n0 + nc];
        }
        __syncthreads();
#pragma unroll
        for (int k = 0; k < 16; ++k) {
            float4 a4 = *(const float4*)&As[k][ty * 4];
            float4 w4 = *(const float4*)&Ws[k][tx * 4];
            float av[4] = {a4.x, a4.y, a4.z, a4.w};
            float wv[4] = {w4.x, w4.y, w4.z, w4.w};
#pragma unroll
            for (int i = 0; i < 4; ++i)
#pragma unroll
                for (int j = 0; j < 4; ++j) acc[i][j] += av[i] * wv[j];
        }
        __syncthreads();
    }
#pragma unroll
    for (int i = 0; i < 4; ++i) {
        int row = m0 + ty * 4 + i;
#pragma unroll
        for (int j = 0; j < 4; ++j) {
            int col = n0 + tx * 4 + j;
            float v = acc[i][j];
            if (doBias) v += bias[col];
            if (MODE == 1) v = fmaxf(v, 0.f);
            if (MODE == 2) {
                int bb = row >> 11, ll = row & (LSEQ - 1);
                int hh = col >> 5, dd = col & 31;
                C[(((size_t)(bb * NHEAD + hh) * LSEQ) + ll) * D_K + dd] = v;
            } else {
                C[(size_t)row * N + col] = v;
            }
        }
    }
}

// QKV fused: blockIdx.z selects {wq,wk,wv}; scatters to [B,H,L,32] at out+z*1M.
__global__ __launch_bounds__(256) void k_qkv(const float* __restrict__ A,
                                             const float* __restrict__ wq,
                                             const float* __restrict__ wk,
                                             const float* __restrict__ wv,
                                             const float* __restrict__ bq,
                                             const float* __restrict__ bk,
                                             const float* __restrict__ bv,
                                             float* __restrict__ out) {
    int z = blockIdx.z;
    const float* W = z == 0 ? wq : (z == 1 ? wk : wv);
    const float* B = z == 0 ? bq : (z == 1 ? bk : bv);
    gemm_body<2>(A, 256, W, 256, B, true, out + (size_t)z * (1 << 20), 256,
                 blockIdx.x * 64, blockIdx.y * 64);
}

// split-K GEMM: blockIdx.z = K-half; partial z to Cbase + z*1M; bias on z=0 only.
__global__ __launch_bounds__(256) void k_gemm_sk(const float* __restrict__ A, int lda,
                                                 const float* __restrict__ W,
                                                 const float* __restrict__ bias,
                                                 float* __restrict__ Cbase,
                                                 int N, int Ksub) {
    int z = blockIdx.z;
    gemm_body<0>(A + (size_t)z * Ksub, lda, W + (size_t)z * Ksub * N, N, bias, z == 0,
                 Cbase + (size_t)z * (1 << 20), Ksub, blockIdx.x * 64, blockIdx.y * 64);
}

// ff1: relu GEMM, N=1024
__global__ __launch_bounds__(256) void k_ff1(const float* __restrict__ A,
                                             const float* __restrict__ W,
                                             const float* __restrict__ bias,
                                             float* __restrict__ C) {
    gemm_body<1>(A, 256, W, 1024, bias, true, C, 256, blockIdx.x * 64, blockIdx.y * 64);
}

// ---------------------------------------------------------------------------
// Fused ProbSparse attention v11 — single pass, d-split, bitonic threshold.
// d-split (R8-verified layout): lanes 0..31 own dims 0..15, lanes 32..63 own
// dims 16..31; lane computes half-dots of keys 2p and 2p+1; one shfl_xor(32)
// per row per tile combines halves; lane keeps key 2p+h.
// q = 32 VGPR (not 64) -> live ~135 < 170 budget (256,3) -> no AGPR shuttle
// (R13's VGPR_Count=84 tell). Keys k0/k1 in registers via full unroll.
// Exact 38th-largest threshold: 128-wide bitonic sort of the candidate list
// (2 regs/lane, shfl-only) -> sorted idx 90 (no LDS atomics, no radix).
// Triple-buffered global_load_lds staging, counted vmcnt(2) + raw s_barrier.
// ---------------------------------------------------------------------------
__device__ __forceinline__ unsigned int sortkey(float f) {
    unsigned int u = __float_as_uint(f);
    return (u & 0x80000000u) ? ~u : (u | 0x80000000u);
}
__device__ __forceinline__ float key2f(unsigned int u) {
    unsigned int b = (u & 0x80000000u) ? (u ^ 0x80000000u) : ~u;
    return __uint_as_float(b);
}
__device__ __forceinline__ void gload_lds16(const float* src, float* ldsDst) {
    __builtin_amdgcn_global_load_lds(
        (const __attribute__((address_space(1))) unsigned int*)src,
        (__attribute__((address_space(3))) unsigned int*)ldsDst,
        16, 0, 0);
}

__global__ __launch_bounds__(256, 3) void k_attn(const float* __restrict__ Q,
                                                 const float* __restrict__ Kt,
                                                 const float* __restrict__ Vt,
                                                 float* __restrict__ ctxb) {
    __shared__ float          Kl[3][2048];      // 24 KB  K tile triple-buffer
    __shared__ unsigned int   lvk[4][2][CAP];   // 4 KB   candidate keys
    __shared__ unsigned short lix[4][2][CAP];   // 2 KB   candidate indices
    __shared__ int            lcnt[4][2];

    const int tid   = threadIdx.x;
    const int lane  = tid & 63;
    const int wid   = tid >> 6;
    // XCD swizzle: grid 4096 = 8 XCDs x 512 (bijective).
    const int lbid  = (blockIdx.x & 7) * 512 + (blockIdx.x >> 3);
    const int bh    = lbid >> 8;                // 16 bh x 256 chunks
    const int chunk = lbid & 255;
    const int row0  = chunk * 8 + wid * 2;      // 2 rows per wave
    const int b     = bh >> 3, hh = bh & 7;
    const int h     = lane >> 5;                // d-half owned by this lane
    const int p     = lane & 31;

    const float* Kb = Kt + (size_t)bh * LSEQ * D_K;
    const float* Vb = Vt + (size_t)bh * LSEQ * D_K;
    const float* qp = Q + ((size_t)bh * LSEQ + row0) * D_K;

    const float scale = 0.17677669529663687f;   // 1/sqrt(32)
    float q0[16], q1[16];
#pragma unroll
    for (int i = 0; i < 16; ++i) {
        q0[i] = qp[h * 16 + i] * scale;
        q1[i] = qp[32 + h * 16 + i] * scale;
    }

    // Stage tile T: wave wid stages granules g = wid*2+{0,1} (g in 0..7).
    // Granule g holds dim-chunk (g&3) of keys 2p + (g>>2), half h, for all p.
#define STAGE(T, SLOT)                                                          \
    {                                                                           \
        const int g0_ = wid * 2, g1_ = wid * 2 + 1;                             \
        gload_lds16(Kb + (size_t)(T) * 2048 + (2 * p + (g0_ >> 2)) * 32         \
                        + h * 16 + (g0_ & 3) * 4, &Kl[SLOT][g0_ * 256]);        \
        gload_lds16(Kb + (size_t)(T) * 2048 + (2 * p + (g1_ >> 2)) * 32         \
                        + h * 16 + (g1_ & 3) * 4, &Kl[SLOT][g1_ * 256]);        \
    }

    // ---- single pass: half-dots -> combine -> registers, lane-max ------
    unsigned int k0[32], k1[32];
    unsigned int lm0 = 0u, lm1 = 0u;

    STAGE(0, 0)
    STAGE(1, 1)
    asm volatile("s_waitcnt vmcnt(2)" ::: "memory");
    __builtin_amdgcn_s_barrier();

#pragma unroll
    for (int t = 0; t < 32; ++t) {
        const int slot = t % 3;               // literal under full unroll
        if (t < 30) STAGE(t + 2, (t + 2) % 3)
        float a0 = 0.f, a1 = 0.f, e0 = 0.f, e1 = 0.f;
#pragma unroll
        for (int c = 0; c < 4; ++c) {
            float4 kva = *(const float4*)&Kl[slot][c * 256 + lane * 4];        // key 2p
            float4 kvb = *(const float4*)&Kl[slot][(4 + c) * 256 + lane * 4];  // key 2p+1
            a0 += q0[c*4+0]*kva.x + q0[c*4+1]*kva.y + q0[c*4+2]*kva.z + q0[c*4+3]*kva.w;
            a1 += q1[c*4+0]*kva.x + q1[c*4+1]*kva.y + q1[c*4+2]*kva.z + q1[c*4+3]*kva.w;
            e0 += q0[c*4+0]*kvb.x + q0[c*4+1]*kvb.y + q0[c*4+2]*kvb.z + q0[c*4+3]*kvb.w;
            e1 += q1[c*4+0]*kvb.x + q1[c*4+1]*kvb.y + q1[c*4+2]*kvb.z + q1[c*4+3]*kvb.w;
        }
        float fA0 = a0 + __shfl_xor(a0, 32);
        float fB0 = e0 + __shfl_xor(e0, 32);
        float fA1 = a1 + __shfl_xor(a1, 32);
        float fB1 = e1 + __shfl_xor(e1, 32);
        k0[t] = sortkey(h ? fB0 : fA0);       // lane keeps key 2p+h
        k1[t] = sortkey(h ? fB1 : fA1);
        if (k0[t] > lm0) lm0 = k0[t];
        if (k1[t] > lm1) lm1 = k1[t];
        if (t < 31) {
            if (t < 30) asm volatile("s_waitcnt vmcnt(2)" ::: "memory");
            else        asm volatile("s_waitcnt vmcnt(0)" ::: "memory");
            __builtin_amdgcn_s_barrier();
        }
    }

    // ---- pivot per row: bitonic-sort 64 lane-maxes, broadcast via shfl --
    unsigned int Tpiv[2];
    float        rmaxf[2];
#pragma unroll
    for (int r = 0; r < 2; ++r) {
        unsigned int v = r ? lm1 : lm0;
#pragma unroll
        for (int k = 2; k <= 64; k <<= 1) {
#pragma unroll
            for (int j = k >> 1; j >= 1; j >>= 1) {
                unsigned int pv = (unsigned int)__shfl_xor((int)v, j);
                bool lower = ((lane & j) == 0);
                bool up    = ((lane & k) == 0);
                unsigned int mn = v < pv ? v : pv;
                unsigned int mx = v < pv ? pv : v;
                v = (lower == up) ? mn : mx;
            }
        }
        Tpiv[r]  = (unsigned int)__shfl((int)v, 26);  // 38th-largest lane-max
        rmaxf[r] = key2f((unsigned int)__shfl((int)v, 63));
    }
    if (lane < 2) lcnt[wid][lane] = 0;

    // ---- push candidates >= pivot from registers -----------------------
#pragma unroll
    for (int j = 0; j < 32; ++j) {
        if (k0[j] >= Tpiv[0]) {
            int s = atomicAdd(&lcnt[wid][0], 1);
            if (s < CAP) { lvk[wid][0][s] = k0[j]; lix[wid][0][s] = (unsigned short)(j * 64 + 2 * p + h); }
        }
        if (k1[j] >= Tpiv[1]) {
            int s = atomicAdd(&lcnt[wid][1], 1);
            if (s < CAP) { lvk[wid][1][s] = k1[j]; lix[wid][1][s] = (unsigned short)(j * 64 + 2 * p + h); }
        }
    }

    // ---- per-row: exact threshold via 128-wide bitonic, softmax, PV ----
#pragma unroll
    for (int r = 0; r < 2; ++r) {
        int cnt = lcnt[wid][r]; if (cnt > CAP) cnt = CAP;

        // load candidates (pad 0 = below any real key), sort ascending over
        // virtual index idx = rr*64 + lane
        unsigned int v0 = (lane < cnt)      ? lvk[wid][r][lane]      : 0u;
        unsigned int v1 = (64 + lane < cnt) ? lvk[wid][r][64 + lane] : 0u;
#pragma unroll
        for (int k = 2; k <= 128; k <<= 1) {
#pragma unroll
            for (int j = k >> 1; j >= 1; j >>= 1) {
                if (j >= 64) {
                    // partner is the other register in the same lane
                    bool up0 = ((lane & k) == 0);   // idx0 = lane; (idx0 & k) with k=128 -> 0 -> true
                    unsigned int mn = v0 < v1 ? v0 : v1;
                    unsigned int mx = v0 < v1 ? v1 : v0;
                    v0 = up0 ? mn : mx;
                    v1 = up0 ? mx : mn;
                } else {
                    unsigned int p0 = (unsigned int)__shfl_xor((int)v0, j);
                    unsigned int p1 = (unsigned int)__shfl_xor((int)v1, j);
                    bool lower = ((lane & j) == 0);
                    bool up0 = (((lane) & k) == 0);
                    bool up1 = (((64 + lane) & k) == 0);
                    v0 = (lower == up0) ? (v0 < p0 ? v0 : p0) : (v0 < p0 ? p0 : v0);
                    v1 = (lower == up1) ? (v1 < p1 ? v1 : p1) : (v1 < p1 ? p1 : v1);
                }
            }
        }
        // ascending: 38th-largest = idx 128-38 = 90 = reg v1 of lane 26
        const unsigned int thrkey = (unsigned int)__shfl((int)v1, 26);

        float psum = 0.f;
        for (int i = lane; i < cnt; i += 64) {
            unsigned int key = lvk[wid][r][i];
            if (key >= thrkey) psum += expf(key2f(key) - rmaxf[r]);
        }
#pragma unroll
        for (int off = 32; off >= 1; off >>= 1) psum += __shfl_xor(psum, off);
        float inv = 1.0f / psum;

        float acc = 0.f;
        for (int i = h; i < cnt; i += 2) {
            unsigned int key = lvk[wid][r][i];
            float w = (key >= thrkey) ? expf(key2f(key) - rmaxf[r]) : 0.f;
            acc += w * Vb[(size_t)lix[wid][r][i] * D_K + p];
        }
        acc += __shfl_xor(acc, 32);
        if (lane < 32)
            ctxb[((size_t)(b * LSEQ) + row0 + r) * D_MODEL + hh * D_K + p] = acc * inv;
    }
}

// ---------------------------------------------------------------------------
// Residual add (two partials) + LayerNorm over 256, in place into h.
// ---------------------------------------------------------------------------
__global__ __launch_bounds__(64) void k_addln2(float* __restrict__ h,
                                               const float* __restrict__ a1,
                                               const float* __restrict__ a2,
                                               const float* __restrict__ g,
                                               const float* __restrict__ bb) {
    int row = blockIdx.x, lane = threadIdx.x;
    float4 hv = *(const float4*)&h[(size_t)row * D_MODEL + lane * 4];
    float4 v1 = *(const float4*)&a1[(size_t)row * D_MODEL + lane * 4];
    float4 v2 = *(const float4*)&a2[(size_t)row * D_MODEL + lane * 4];
    float x0 = hv.x + v1.x + v2.x, x1 = hv.y + v1.y + v2.y;
    float x2 = hv.z + v1.z + v2.z, x3 = hv.w + v1.w + v2.w;
    float s = x0 + x1 + x2 + x3;
#pragma unroll
    for (int off = 32; off >= 1; off >>= 1) s += __shfl_xor(s, off);
    float mean = s * (1.0f / 256.0f);
    float d0 = x0 - mean, d1 = x1 - mean, d2 = x2 - mean, d3 = x3 - mean;
    float vs = d0 * d0 + d1 * d1 + d2 * d2 + d3 * d3;
#pragma unroll
    for (int off = 32; off >= 1; off >>= 1) vs += __shfl_xor(vs, off);
    float inv = rsqrtf(vs * (1.0f / 256.0f) + 1e-5f);
    float4 gv = *(const float4*)&g[lane * 4];
    float4 bv = *(const float4*)&bb[lane * 4];
    float4 o;
    o.x = d0 * inv * gv.x + bv.x;
    o.y = d1 * inv * gv.y + bv.y;
    o.z = d2 * inv * gv.z + bv.z;
    o.w = d3 * inv * gv.w + bv.w;
    *(float4*)&h[(size_t)row * D_MODEL + lane * 4] = o;
}

// ---------------------------------------------------------------------------
// Decoder head
// ---------------------------------------------------------------------------
__global__ __launch_bounds__(64) void k_dec(const float* __restrict__ h,
                                            const float* __restrict__ w,
                                            const float* __restrict__ b,
                                            float* __restrict__ out) {
    int row = blockIdx.x, lane = threadIdx.x;
    int c = lane & 7, part = lane >> 3;   // 8 parts x 32 dims
    float acc = 0.f;
    int d0 = part * 32;
#pragma unroll
    for (int dd = 0; dd < 32; ++dd) acc += h[(size_t)row * D_MODEL + d0 + dd] * w[(d0 + dd) * 8 + c];
    acc += __shfl_xor(acc, 8);
    acc += __shfl_xor(acc, 16);
    acc += __shfl_xor(acc, 32);
    if (lane < 8) out[(size_t)row * 8 + c] = acc + b[c];
}

// ---------------------------------------------------------------------------
extern "C" void kernel_launch(void* const* d_in, const int* in_sizes, int n_in,
                              void* d_out, int out_size, void* d_ws, size_t ws_size,
                              hipStream_t stream) {
    const float* x     = (const float*)d_in[0];
    const float* emb_w = (const float*)d_in[1];
    const float* emb_b = (const float*)d_in[2];
    const float* wq    = (const float*)d_in[3];
    const float* bq    = (const float*)d_in[4];
    const float* wk    = (const float*)d_in[5];
    const float* bk    = (const float*)d_in[6];
    const float* wv    = (const float*)d_in[7];
    const float* bv    = (const float*)d_in[8];
    const float* wo    = (const float*)d_in[9];
    const float* bo    = (const float*)d_in[10];
    const float* ln1_g = (const float*)d_in[11];
    const float* ln1_b = (const float*)d_in[12];
    const float* ln2_g = (const float*)d_in[13];
    const float* ln2_b = (const float*)d_in[14];
    const float* ff1_w = (const float*)d_in[15];
    const float* ff1_b = (const float*)d_in[16];
    const float* ff2_w = (const float*)d_in[17];
    const float* ff2_b = (const float*)d_in[18];
    const float* dec_w = (const float*)d_in[19];
    const float* dec_b = (const float*)d_in[20];

    float* ws   = (float*)d_ws;
    float* h    = ws;                      // 4096*256   = 1M floats
    float* qb   = h    + (1 << 20);        // qb/kb/vb: [B,H,L,32] each 1M
    float* kb   = qb   + (1 << 20);
    float* vb   = kb   + (1 << 20);
    float* ctxb = vb   + (1 << 20);
    float* ffb  = ctxb + (1 << 20);        // 4096*1024 = 4M

    k_embed<<<ROWS, 256, 0, stream>>>(x, emb_w, emb_b, h);

    for (int l = 0; l < 2; ++l) {
        const float* wql = wq + (size_t)l * 65536;  const float* bql = bq + l * 256;
        const float* wkl = wk + (size_t)l * 65536;  const float* bkl = bk + l * 256;
        const float* wvl = wv + (size_t)l * 65536;  const float* bvl = bv + l * 256;
        const float* wol = wo + (size_t)l * 65536;  const float* bol = bo + l * 256;

        dim3 gq(64, 4, 3);
        k_qkv<<<gq, 256, 0, stream>>>(h, wql, wkl, wvl, bql, bkl, bvl, qb);

        k_attn<<<NHEAD * BATCH * 256, 256, 0, stream>>>(qb, kb, vb, ctxb);

        // wo: split-K (128 x 2) -> partials in qb, kb (free after attn)
        dim3 gsk(64, 4, 2);
        k_gemm_sk<<<gsk, 256, 0, stream>>>(ctxb, 256, wol, bol, qb, 256, 128);
        k_addln2<<<ROWS, 64, 0, stream>>>(h, qb, kb, ln1_g + l * 256, ln1_b + l * 256);

        dim3 gf1(64, 16);
        k_ff1<<<gf1, 256, 0, stream>>>(h, ff1_w + (size_t)l * 262144, ff1_b + l * 1024, ffb);

        // ff2: split-K (512 x 2) -> partials in qb, kb
        k_gemm_sk<<<gsk, 256, 0, stream>>>(ffb, 1024, ff2_w + (size_t)l * 262144,
                                           ff2_b + l * 256, qb, 256, 512);
        k_addln2<<<ROWS, 64, 0, stream>>>(h, qb, kb, ln2_g + l * 256, ln2_b + l * 256);
    }

    k_dec<<<ROWS, 64, 0, stream>>>(h, dec_w, dec_b, (float*)d_out);
}